// Round 1
// baseline (1399.778 us; speedup 1.0000x reference)
//
#include <hip/hip_runtime.h>
#include <hip/hip_bf16.h>

typedef unsigned int  uint32;
typedef unsigned short ushort16;

#define B_   32
#define NQ_  300
#define D_   256
#define H_   8
#define HD_  32
#define L_   3
#define P_   4
#define S_   8400
#define FFN_ 1024
#define M1   (B_*NQ_)    // 9600
#define MV   (B_*S_)     // 268800

// ---------- helpers ----------
__device__ inline ushort16 f2bf(float x) {
  uint32 u = __float_as_uint(x);
  uint32 r = u + 0x7fffu + ((u >> 16) & 1u);
  return (ushort16)(r >> 16);
}
__device__ inline float bf2f(ushort16 v) {
  return __uint_as_float(((uint32)v) << 16);
}

// ---------- elementwise add (float4) ----------
__global__ __launch_bounds__(256) void rt_add(const float* __restrict__ a,
                                              const float* __restrict__ b,
                                              float* __restrict__ o, int n4)
{
  int i = blockIdx.x * 256 + threadIdx.x;
  if (i < n4) {
    float4 x = ((const float4*)a)[i];
    float4 y = ((const float4*)b)[i];
    float4 z; z.x = x.x + y.x; z.y = x.y + y.y; z.z = x.z + y.z; z.w = x.w + y.w;
    ((float4*)o)[i] = z;
  }
}

// ---------- tiled fp32 GEMM: C[M,N] = A[M,K] @ W[K,N] + bias, (opt) *scale, relu ----------
// out_mode 0: C row-major f32.  out_mode 1: scatter to value[b][h][s][hd] as bf16.
#define BM 64
#define BN 64
#define BK 16
__global__ __launch_bounds__(256) void rt_gemm(
    const float* __restrict__ A, const float* __restrict__ W,
    const float* __restrict__ bias, float* __restrict__ C,
    ushort16* __restrict__ Cbf,
    int M, int N, int K, float scale, int relu, int out_mode)
{
  __shared__ __align__(16) float As[BK][BM + 4];
  __shared__ __align__(16) float Bs[BK][BN];
  const int tid = threadIdx.x;
  const int bm = blockIdx.y * BM, bn = blockIdx.x * BN;
  const int tx = tid & 15, ty = tid >> 4;
  const int r0 = ty * 4, c0 = tx * 4;
  const int arow = tid >> 2, akc = (tid & 3) * 4;
  const int brow = tid >> 4, bcol = (tid & 15) * 4;
  float acc[4][4] = {{0.f,0.f,0.f,0.f},{0.f,0.f,0.f,0.f},{0.f,0.f,0.f,0.f},{0.f,0.f,0.f,0.f}};

  for (int k0 = 0; k0 < K; k0 += BK) {
    float4 av = *(const float4*)(A + (size_t)(bm + arow) * K + k0 + akc);
    float4 bvv;
    {
      int gc = bn + bcol;
      const float* Wp = W + (size_t)(k0 + brow) * N + gc;
      if (gc + 3 < N) bvv = *(const float4*)Wp;
      else {
        bvv.x = (gc + 0 < N) ? Wp[0] : 0.f;
        bvv.y = (gc + 1 < N) ? Wp[1] : 0.f;
        bvv.z = (gc + 2 < N) ? Wp[2] : 0.f;
        bvv.w = (gc + 3 < N) ? Wp[3] : 0.f;
      }
    }
    As[akc + 0][arow] = av.x;
    As[akc + 1][arow] = av.y;
    As[akc + 2][arow] = av.z;
    As[akc + 3][arow] = av.w;
    *(float4*)&Bs[brow][bcol] = bvv;
    __syncthreads();
#pragma unroll
    for (int kk = 0; kk < BK; ++kk) {
      float4 a  = *(const float4*)&As[kk][r0];
      float4 bb = *(const float4*)&Bs[kk][c0];
      acc[0][0] += a.x * bb.x; acc[0][1] += a.x * bb.y; acc[0][2] += a.x * bb.z; acc[0][3] += a.x * bb.w;
      acc[1][0] += a.y * bb.x; acc[1][1] += a.y * bb.y; acc[1][2] += a.y * bb.z; acc[1][3] += a.y * bb.w;
      acc[2][0] += a.z * bb.x; acc[2][1] += a.z * bb.y; acc[2][2] += a.z * bb.z; acc[2][3] += a.z * bb.w;
      acc[3][0] += a.w * bb.x; acc[3][1] += a.w * bb.y; acc[3][2] += a.w * bb.z; acc[3][3] += a.w * bb.w;
    }
    __syncthreads();
  }
#pragma unroll
  for (int i = 0; i < 4; i++) {
    int row = bm + r0 + i;
    if (row >= M) continue;
#pragma unroll
    for (int j = 0; j < 4; j++) {
      int col = bn + c0 + j;
      if (col >= N) continue;
      float v = (acc[i][j] + bias[col]) * scale;
      if (relu) v = fmaxf(v, 0.f);
      if (out_mode == 0) {
        C[(size_t)row * N + col] = v;
      } else {
        int bb = row / S_, s = row - bb * S_;
        int hh = col >> 5, hd = col & 31;
        Cbf[(((size_t)bb * H_ + hh) * S_ + s) * HD_ + hd] = f2bf(v);
      }
    }
  }
}

// ---------- self-attention: one block per (b,h). Online softmax, 2-pass. ----------
__global__ __launch_bounds__(320) void rt_attn(
    const float* __restrict__ Q, const float* __restrict__ Kk,
    const float* __restrict__ V, float* __restrict__ O)
{
  __shared__ __align__(16) float    Ks[NQ_][HD_];
  __shared__ __align__(16) ushort16 Vs[NQ_][HD_];
  const int b = blockIdx.x >> 3, h = blockIdx.x & 7;
  const int tid = threadIdx.x;
  for (int idx = tid; idx < NQ_ * HD_; idx += 320) {
    int n = idx >> 5, hd = idx & 31;
    size_t g = (size_t)(b * NQ_ + n) * D_ + h * HD_ + hd;
    Ks[n][hd] = Kk[g];
    Vs[n][hd] = f2bf(V[g]);
  }
  __syncthreads();
  if (tid < NQ_) {
    float4 qv[8];
    const float* qp = Q + (size_t)(b * NQ_ + tid) * D_ + h * HD_;
#pragma unroll
    for (int i = 0; i < 8; i++) qv[i] = *(const float4*)(qp + 4 * i);

    float m = -1e30f, ssum = 0.f;
    for (int n = 0; n < NQ_; n++) {
      const float4* kr = (const float4*)Ks[n];
      float s = 0.f;
#pragma unroll
      for (int i = 0; i < 8; i++) {
        float4 kv = kr[i];
        s += qv[i].x * kv.x + qv[i].y * kv.y + qv[i].z * kv.z + qv[i].w * kv.w;
      }
      float nm = fmaxf(m, s);
      ssum = ssum * __expf(m - nm) + __expf(s - nm);
      m = nm;
    }
    float o[32];
#pragma unroll
    for (int i = 0; i < 32; i++) o[i] = 0.f;
    for (int n = 0; n < NQ_; n++) {
      const float4* kr = (const float4*)Ks[n];
      float s = 0.f;
#pragma unroll
      for (int i = 0; i < 8; i++) {
        float4 kv = kr[i];
        s += qv[i].x * kv.x + qv[i].y * kv.y + qv[i].z * kv.z + qv[i].w * kv.w;
      }
      float p = __expf(s - m);
      const uint4* vr = (const uint4*)Vs[n];
#pragma unroll
      for (int i = 0; i < 4; i++) {
        uint4 u = vr[i];
        o[i*8+0] += p * __uint_as_float(u.x << 16);
        o[i*8+1] += p * __uint_as_float(u.x & 0xffff0000u);
        o[i*8+2] += p * __uint_as_float(u.y << 16);
        o[i*8+3] += p * __uint_as_float(u.y & 0xffff0000u);
        o[i*8+4] += p * __uint_as_float(u.z << 16);
        o[i*8+5] += p * __uint_as_float(u.z & 0xffff0000u);
        o[i*8+6] += p * __uint_as_float(u.w << 16);
        o[i*8+7] += p * __uint_as_float(u.w & 0xffff0000u);
      }
    }
    float inv = 1.f / ssum;
    float* op = O + (size_t)(b * NQ_ + tid) * D_ + h * HD_;
#pragma unroll
    for (int i = 0; i < 8; i++) {
      float4 t;
      t.x = o[i*4+0] * inv; t.y = o[i*4+1] * inv;
      t.z = o[i*4+2] * inv; t.w = o[i*4+3] * inv;
      *(float4*)(op + 4 * i) = t;
    }
  }
}

// ---------- LayerNorm: out = LN(X + R) * g + b.  One wave per row (D=256 => 4/lane). ----------
__global__ __launch_bounds__(256) void rt_ln(
    const float* __restrict__ X, const float* __restrict__ R,
    const float* __restrict__ g, const float* __restrict__ be,
    float* __restrict__ O, int rows)
{
  int row = blockIdx.x * 4 + (threadIdx.x >> 6);
  int lane = threadIdx.x & 63;
  if (row >= rows) return;
  size_t base = (size_t)row * D_ + lane * 4;
  float4 x = *(const float4*)(X + base);
  float4 r = *(const float4*)(R + base);
  float v0 = x.x + r.x, v1 = x.y + r.y, v2 = x.z + r.z, v3 = x.w + r.w;
  float s = v0 + v1 + v2 + v3;
  float sq = v0*v0 + v1*v1 + v2*v2 + v3*v3;
#pragma unroll
  for (int o = 32; o >= 1; o >>= 1) { s += __shfl_xor(s, o); sq += __shfl_xor(sq, o); }
  float mean = s * (1.f / D_);
  float var  = sq * (1.f / D_) - mean * mean;
  float inv  = 1.f / sqrtf(var + 1e-5f);
  int c = lane * 4;
  float4 gv = *(const float4*)(g + c);
  float4 bv = *(const float4*)(be + c);
  float4 o4;
  o4.x = (v0 - mean) * inv * gv.x + bv.x;
  o4.y = (v1 - mean) * inv * gv.y + bv.y;
  o4.z = (v2 - mean) * inv * gv.z + bv.z;
  o4.w = (v3 - mean) * inv * gv.w + bv.w;
  *(float4*)(O + base) = o4;
}

// ---------- attention-weight softmax over 12 contiguous values per (b,q,h) ----------
__global__ __launch_bounds__(256) void rt_awsm(float* __restrict__ aw, int groups)
{
  int gidx = blockIdx.x * 256 + threadIdx.x;
  if (gidx >= groups) return;
  float* p = aw + (size_t)gidx * 12;
  float e[12]; float m = -1e30f;
#pragma unroll
  for (int i = 0; i < 12; i++) { e[i] = p[i]; m = fmaxf(m, e[i]); }
  float s = 0.f;
#pragma unroll
  for (int i = 0; i < 12; i++) { e[i] = __expf(e[i] - m); s += e[i]; }
  float inv = 1.f / s;
#pragma unroll
  for (int i = 0; i < 12; i++) p[i] = e[i] * inv;
}

// ---------- deformable sampling: thread = (b,q,h,hd); coalesced over hd ----------
__device__ inline float rt_samp(const ushort16* vl, int xi, int yi, int Wl) {
  if (xi < 0 || xi >= Wl || yi < 0 || yi >= Wl) return 0.f;
  return bf2f(vl[(size_t)(yi * Wl + xi) * HD_]);
}

__global__ __launch_bounds__(256) void rt_deform(
    const ushort16* __restrict__ value,   // [B][H][S][HD] bf16
    const float* __restrict__ off,        // [B][NQ][H][L][P][2]
    const float* __restrict__ aw,         // [B][NQ][H][12] (softmaxed)
    const float* __restrict__ ref,        // [B][NQ][1][4]
    float* __restrict__ O)                // [B][NQ][D]
{
  int gid = blockIdx.x * 256 + threadIdx.x;
  int hd  = gid & 31;
  int bqh = gid >> 5;
  int h   = bqh & 7;
  int bq  = bqh >> 3;
  int b   = bq / NQ_;
  const float* rp = ref + (size_t)bq * 4;
  float rx = rp[0], ry = rp[1];
  float rw = rp[2] * 0.125f, rh = rp[3] * 0.125f;   // * 0.5 / P
  const float* op = off + (size_t)bqh * 24;
  const float* ap = aw  + (size_t)bqh * 12;
  const ushort16* vb = value + ((size_t)b * H_ + h) * (size_t)S_ * HD_ + hd;
  float acc = 0.f;
  const int starts[3] = {0, 6400, 8000};
  const int dims[3]   = {80, 40, 20};
#pragma unroll
  for (int l = 0; l < L_; l++) {
    const int Wl = dims[l];
    const ushort16* vl = vb + (size_t)starts[l] * HD_;
#pragma unroll
    for (int p = 0; p < P_; p++) {
      int ip = l * P_ + p;
      float w = ap[ip];
      float x = (rx + op[ip*2+0] * rw) * Wl - 0.5f;
      float y = (ry + op[ip*2+1] * rh) * Wl - 0.5f;
      float x0f = floorf(x), y0f = floorf(y);
      int   x0 = (int)x0f,  y0 = (int)y0f;
      float wx1 = x - x0f, wy1 = y - y0f;
      float wx0 = 1.f - wx1, wy0 = 1.f - wy1;
      float v00 = rt_samp(vl, x0,     y0,     Wl);
      float v10 = rt_samp(vl, x0 + 1, y0,     Wl);
      float v01 = rt_samp(vl, x0,     y0 + 1, Wl);
      float v11 = rt_samp(vl, x0 + 1, y0 + 1, Wl);
      acc += w * (v00 * wx0 * wy0 + v10 * wx1 * wy0 + v01 * wx0 * wy1 + v11 * wx1 * wy1);
    }
  }
  O[gid] = acc;
}

// ---------- launch ----------
extern "C" void kernel_launch(void* const* d_in, const int* in_sizes, int n_in,
                              void* d_out, int out_size, void* d_ws, size_t ws_size,
                              hipStream_t stream)
{
  const float* hs   = (const float*)d_in[0];
  const float* pos  = (const float*)d_in[1];
  const float* ref  = (const float*)d_in[2];
  const float* ehs  = (const float*)d_in[3];
  const float* Wq   = (const float*)d_in[4];
  const float* Wk   = (const float*)d_in[5];
  const float* Wv   = (const float*)d_in[6];
  const float* Wo   = (const float*)d_in[7];
  const float* Woff = (const float*)d_in[8];
  const float* Waw  = (const float*)d_in[9];
  const float* Wval = (const float*)d_in[10];
  const float* Wout = (const float*)d_in[11];
  const float* W1   = (const float*)d_in[12];
  const float* W2   = (const float*)d_in[13];
  const float* bq   = (const float*)d_in[14];
  const float* bk   = (const float*)d_in[15];
  const float* bvv  = (const float*)d_in[16];
  const float* bo   = (const float*)d_in[17];
  const float* boff = (const float*)d_in[18];
  const float* baw  = (const float*)d_in[19];
  const float* bval = (const float*)d_in[20];
  const float* bout = (const float*)d_in[21];
  const float* b1   = (const float*)d_in[22];
  const float* b2   = (const float*)d_in[23];
  const float* ln1g = (const float*)d_in[24];
  const float* ln1b = (const float*)d_in[25];
  const float* ln2g = (const float*)d_in[26];
  const float* ln2b = (const float*)d_in[27];
  const float* ln3g = (const float*)d_in[28];
  const float* ln3b = (const float*)d_in[29];
  float* out = (float*)d_out;

  // workspace layout (floats). value stored as bf16 (ushort). total = 266.65 MB
  float* ws = (float*)d_ws;
  ushort16* value = (ushort16*)ws;               // 68,812,800 ushort = 34,406,400 fl
  float* hp   = ws + 34406400;
  float* qb   = ws + 36864000;
  float* kb   = ws + 39321600;
  float* vb   = ws + 41779200;
  float* t0   = ws + 44236800;
  float* t1   = ws + 46694400;
  float* hs1  = ws + 49152000;
  float* hs2  = ws + 51609600;
  float* offb = ws + 54067200;
  float* awb  = ws + 55910400;
  float* ffn1 = ws + 56832000;                   // end 66,662,400 fl

  const float qscale = 0.17677669529663687f;     // HD^-0.5

  // 1) value projection -> bf16 scatter [B][H][S][HD]
  rt_gemm<<<dim3(D_/BN, MV/BM), 256, 0, stream>>>(ehs, Wval, bval, nullptr, value,
                                                  MV, D_, D_, 1.f, 0, 1);
  // 2) hp = hs + pos
  rt_add<<<dim3(M1*D_/4/256), 256, 0, stream>>>(hs, pos, hp, M1*D_/4);
  // 3) q,k,v projections
  rt_gemm<<<dim3(D_/BN, M1/BM), 256, 0, stream>>>(hp, Wq, bq, qb, nullptr, M1, D_, D_, qscale, 0, 0);
  rt_gemm<<<dim3(D_/BN, M1/BM), 256, 0, stream>>>(hp, Wk, bk, kb, nullptr, M1, D_, D_, 1.f, 0, 0);
  rt_gemm<<<dim3(D_/BN, M1/BM), 256, 0, stream>>>(hs, Wv, bvv, vb, nullptr, M1, D_, D_, 1.f, 0, 0);
  // 4) self-attention -> t0
  rt_attn<<<dim3(B_*H_), 320, 0, stream>>>(qb, kb, vb, t0);
  // 5) output proj -> t1 ; LN1 -> hs1
  rt_gemm<<<dim3(D_/BN, M1/BM), 256, 0, stream>>>(t0, Wo, bo, t1, nullptr, M1, D_, D_, 1.f, 0, 0);
  rt_ln<<<dim3(M1/4), 256, 0, stream>>>(hs, t1, ln1g, ln1b, hs1, M1);
  // 6) hp = hs1 + pos ; off & aw projections ; aw softmax
  rt_add<<<dim3(M1*D_/4/256), 256, 0, stream>>>(hs1, pos, hp, M1*D_/4);
  rt_gemm<<<dim3(192/BN, M1/BM), 256, 0, stream>>>(hp, Woff, boff, offb, nullptr, M1, 192, D_, 1.f, 0, 0);
  rt_gemm<<<dim3((96+BN-1)/BN, M1/BM), 256, 0, stream>>>(hp, Waw, baw, awb, nullptr, M1, 96, D_, 1.f, 0, 0);
  rt_awsm<<<dim3(B_*NQ_*H_/256), 256, 0, stream>>>(awb, B_*NQ_*H_);
  // 7) deformable sampling -> t0 ; out proj -> t1 ; LN2 -> hs2
  rt_deform<<<dim3(M1*D_/256), 256, 0, stream>>>(value, offb, awb, ref, t0);
  rt_gemm<<<dim3(D_/BN, M1/BM), 256, 0, stream>>>(t0, Wout, bout, t1, nullptr, M1, D_, D_, 1.f, 0, 0);
  rt_ln<<<dim3(M1/4), 256, 0, stream>>>(hs1, t1, ln2g, ln2b, hs2, M1);
  // 8) FFN ; LN3 -> out
  rt_gemm<<<dim3(FFN_/BN, M1/BM), 256, 0, stream>>>(hs2, W1, b1, ffn1, nullptr, M1, FFN_, D_, 1.f, 1, 0);
  rt_gemm<<<dim3(D_/BN, M1/BM), 256, 0, stream>>>(ffn1, W2, b2, t1, nullptr, M1, D_, FFN_, 1.f, 0, 0);
  rt_ln<<<dim3(M1/4), 256, 0, stream>>>(hs2, t1, ln3g, ln3b, out, M1);
}

// Round 2
// 821.015 us; speedup vs baseline: 1.7049x; 1.7049x over previous
//
#include <hip/hip_runtime.h>
#include <hip/hip_bf16.h>

typedef unsigned int  uint32;
typedef unsigned short ushort16;
typedef __bf16 bfx8 __attribute__((ext_vector_type(8)));
typedef float  f32x4 __attribute__((ext_vector_type(4)));

#define B_   32
#define NQ_  300
#define D_   256
#define H_   8
#define HD_  32
#define L_   3
#define P_   4
#define S_   8400
#define FFN_ 1024
#define M1   (B_*NQ_)    // 9600
#define MV   (B_*S_)     // 268800

// ---------- helpers ----------
__device__ inline ushort16 f2bf(float x) {
  uint32 u = __float_as_uint(x);
  uint32 r = u + 0x7fffu + ((u >> 16) & 1u);
  return (ushort16)(r >> 16);
}
__device__ inline float bf2f(ushort16 v) {
  return __uint_as_float(((uint32)v) << 16);
}

// ---------- elementwise add (float4) ----------
__global__ __launch_bounds__(256) void rt_add(const float* __restrict__ a,
                                              const float* __restrict__ b,
                                              float* __restrict__ o, int n4)
{
  int i = blockIdx.x * 256 + threadIdx.x;
  if (i < n4) {
    float4 x = ((const float4*)a)[i];
    float4 y = ((const float4*)b)[i];
    float4 z; z.x = x.x + y.x; z.y = x.y + y.y; z.z = x.z + y.z; z.w = x.w + y.w;
    ((float4*)o)[i] = z;
  }
}

// ---------- weight transpose+convert: W[K,N] f32 -> WT[Npad,K] bf16 (zero pad) ----------
__global__ __launch_bounds__(256) void rt_wt(const float* __restrict__ W,
                                             ushort16* __restrict__ WT,
                                             int K, int N, int Npad)
{
  __shared__ float t[32][33];
  int n0 = blockIdx.x * 32, k0 = blockIdx.y * 32;
  int c = threadIdx.x & 31, r = threadIdx.x >> 5;   // 32 x 8
#pragma unroll
  for (int i = 0; i < 4; i++) {
    int kk = k0 + r + i * 8;
    int nn = n0 + c;
    t[r + i * 8][c] = (nn < N) ? W[(size_t)kk * N + nn] : 0.f;
  }
  __syncthreads();
#pragma unroll
  for (int i = 0; i < 4; i++) {
    int nn = n0 + r + i * 8;
    int kk = k0 + c;
    if (nn < Npad) WT[(size_t)nn * K + kk] = f2bf(t[c][r + i * 8]);
  }
}

// ---------- MFMA bf16 GEMM: C[M,N] = A[M,K](f32) @ BT[Npad,K](bf16)^T + bias ----------
// mode 0: f32 C.  mode 1: f32 C with relu.  mode 2: bf16 scatter to value[b][h][s][hd].
#define GBM 128
#define GBN 128
#define GBK 32
#define LDP 40   // LDS row pitch in bf16 elems (80 B) — keeps ds_read ~2-way

__global__ __launch_bounds__(256) void rt_mgemm(
    const float* __restrict__ A, const ushort16* __restrict__ BT,
    const float* __restrict__ bias, float* __restrict__ C,
    ushort16* __restrict__ Vout,
    int M, int N, int K, float scale, int mode)
{
  __shared__ __align__(16) ushort16 As[GBM][LDP];
  __shared__ __align__(16) ushort16 Bs[GBN][LDP];
  const int tid  = threadIdx.x;
  const int lane = tid & 63;
  const int w    = tid >> 6;
  const int wr   = (w >> 1) * 64;
  const int wc   = (w & 1) * 64;
  const int bm   = blockIdx.y * GBM;
  const int bn   = blockIdx.x * GBN;
  const int l15  = lane & 15;
  const int l4   = lane >> 4;

  f32x4 acc[4][4];
#pragma unroll
  for (int i = 0; i < 4; i++)
#pragma unroll
    for (int j = 0; j < 4; j++)
      acc[i][j] = (f32x4){0.f, 0.f, 0.f, 0.f};

  const int arow = tid >> 3, akc = tid & 7;   // A: 8 x 16B-f32 chunks per row
  const int brow = tid >> 2, bkc = tid & 3;   // B: 4 x 16B-bf16 chunks per row

  for (int k0 = 0; k0 < K; k0 += GBK) {
    // stage A (f32 -> bf16)
#pragma unroll
    for (int i = 0; i < 4; i++) {
      int row = arow + i * 32;
      f32x4 v = *(const f32x4*)(A + (size_t)(bm + row) * K + k0 + akc * 4);
      uint2 u;
      u.x = (uint32)f2bf(v.x) | ((uint32)f2bf(v.y) << 16);
      u.y = (uint32)f2bf(v.z) | ((uint32)f2bf(v.w) << 16);
      *(uint2*)(&As[row][akc * 4]) = u;
    }
    // stage B (bf16 passthrough)
#pragma unroll
    for (int i = 0; i < 2; i++) {
      int row = brow + i * 64;
      uint4 v = *(const uint4*)(BT + (size_t)(bn + row) * K + k0 + bkc * 8);
      *(uint4*)(&Bs[row][bkc * 8]) = v;
    }
    __syncthreads();

    bfx8 af[4], bg[4];
#pragma unroll
    for (int mi = 0; mi < 4; mi++)
      af[mi] = *(const bfx8*)(&As[wr + mi * 16 + l15][l4 * 8]);
#pragma unroll
    for (int ni = 0; ni < 4; ni++)
      bg[ni] = *(const bfx8*)(&Bs[wc + ni * 16 + l15][l4 * 8]);
#pragma unroll
    for (int mi = 0; mi < 4; mi++)
#pragma unroll
      for (int ni = 0; ni < 4; ni++)
        acc[mi][ni] = __builtin_amdgcn_mfma_f32_16x16x32_bf16(af[mi], bg[ni], acc[mi][ni], 0, 0, 0);
    __syncthreads();
  }

#pragma unroll
  for (int mi = 0; mi < 4; mi++) {
#pragma unroll
    for (int ni = 0; ni < 4; ni++) {
      int col = bn + wc + ni * 16 + l15;
      if (col >= N) continue;
      float bv = bias[col];
#pragma unroll
      for (int r = 0; r < 4; r++) {
        int row = bm + wr + mi * 16 + l4 * 4 + r;
        float vv = (acc[mi][ni][r] + bv) * scale;
        if (mode == 1) vv = fmaxf(vv, 0.f);
        if (mode == 2) {
          int bb = row / S_, s = row - bb * S_;
          int hh = col >> 5, hd = col & 31;
          Vout[(((size_t)bb * H_ + hh) * S_ + s) * HD_ + hd] = f2bf(vv);
        } else {
          C[(size_t)row * N + col] = vv;
        }
      }
    }
  }
}

// ---------- self-attention: one block per (b,h). Online softmax, 2-pass. ----------
__global__ __launch_bounds__(320) void rt_attn(
    const float* __restrict__ Q, const float* __restrict__ Kk,
    const float* __restrict__ V, float* __restrict__ O)
{
  __shared__ __align__(16) float    Ks[NQ_][HD_];
  __shared__ __align__(16) ushort16 Vs[NQ_][HD_];
  const int b = blockIdx.x >> 3, h = blockIdx.x & 7;
  const int tid = threadIdx.x;
  for (int idx = tid; idx < NQ_ * HD_; idx += 320) {
    int n = idx >> 5, hd = idx & 31;
    size_t g = (size_t)(b * NQ_ + n) * D_ + h * HD_ + hd;
    Ks[n][hd] = Kk[g];
    Vs[n][hd] = f2bf(V[g]);
  }
  __syncthreads();
  if (tid < NQ_) {
    float4 qv[8];
    const float* qp = Q + (size_t)(b * NQ_ + tid) * D_ + h * HD_;
#pragma unroll
    for (int i = 0; i < 8; i++) qv[i] = *(const float4*)(qp + 4 * i);

    float m = -1e30f, ssum = 0.f;
    for (int n = 0; n < NQ_; n++) {
      const float4* kr = (const float4*)Ks[n];
      float s = 0.f;
#pragma unroll
      for (int i = 0; i < 8; i++) {
        float4 kv = kr[i];
        s += qv[i].x * kv.x + qv[i].y * kv.y + qv[i].z * kv.z + qv[i].w * kv.w;
      }
      float nm = fmaxf(m, s);
      ssum = ssum * __expf(m - nm) + __expf(s - nm);
      m = nm;
    }
    float o[32];
#pragma unroll
    for (int i = 0; i < 32; i++) o[i] = 0.f;
    for (int n = 0; n < NQ_; n++) {
      const float4* kr = (const float4*)Ks[n];
      float s = 0.f;
#pragma unroll
      for (int i = 0; i < 8; i++) {
        float4 kv = kr[i];
        s += qv[i].x * kv.x + qv[i].y * kv.y + qv[i].z * kv.z + qv[i].w * kv.w;
      }
      float p = __expf(s - m);
      const uint4* vr = (const uint4*)Vs[n];
#pragma unroll
      for (int i = 0; i < 4; i++) {
        uint4 u = vr[i];
        o[i*8+0] += p * __uint_as_float(u.x << 16);
        o[i*8+1] += p * __uint_as_float(u.x & 0xffff0000u);
        o[i*8+2] += p * __uint_as_float(u.y << 16);
        o[i*8+3] += p * __uint_as_float(u.y & 0xffff0000u);
        o[i*8+4] += p * __uint_as_float(u.z << 16);
        o[i*8+5] += p * __uint_as_float(u.z & 0xffff0000u);
        o[i*8+6] += p * __uint_as_float(u.w << 16);
        o[i*8+7] += p * __uint_as_float(u.w & 0xffff0000u);
      }
    }
    float inv = 1.f / ssum;
    float* op = O + (size_t)(b * NQ_ + tid) * D_ + h * HD_;
#pragma unroll
    for (int i = 0; i < 8; i++) {
      float4 t;
      t.x = o[i*4+0] * inv; t.y = o[i*4+1] * inv;
      t.z = o[i*4+2] * inv; t.w = o[i*4+3] * inv;
      *(float4*)(op + 4 * i) = t;
    }
  }
}

// ---------- LayerNorm: out = LN(X + R) * g + b.  One wave per row. ----------
__global__ __launch_bounds__(256) void rt_ln(
    const float* __restrict__ X, const float* __restrict__ R,
    const float* __restrict__ g, const float* __restrict__ be,
    float* __restrict__ O, int rows)
{
  int row = blockIdx.x * 4 + (threadIdx.x >> 6);
  int lane = threadIdx.x & 63;
  if (row >= rows) return;
  size_t base = (size_t)row * D_ + lane * 4;
  float4 x = *(const float4*)(X + base);
  float4 r = *(const float4*)(R + base);
  float v0 = x.x + r.x, v1 = x.y + r.y, v2 = x.z + r.z, v3 = x.w + r.w;
  float s = v0 + v1 + v2 + v3;
  float sq = v0*v0 + v1*v1 + v2*v2 + v3*v3;
#pragma unroll
  for (int o = 32; o >= 1; o >>= 1) { s += __shfl_xor(s, o); sq += __shfl_xor(sq, o); }
  float mean = s * (1.f / D_);
  float var  = sq * (1.f / D_) - mean * mean;
  float inv  = 1.f / sqrtf(var + 1e-5f);
  int c = lane * 4;
  float4 gv = *(const float4*)(g + c);
  float4 bv = *(const float4*)(be + c);
  float4 o4;
  o4.x = (v0 - mean) * inv * gv.x + bv.x;
  o4.y = (v1 - mean) * inv * gv.y + bv.y;
  o4.z = (v2 - mean) * inv * gv.z + bv.z;
  o4.w = (v3 - mean) * inv * gv.w + bv.w;
  *(float4*)(O + base) = o4;
}

// ---------- attention-weight softmax over 12 contiguous values per (b,q,h) ----------
__global__ __launch_bounds__(256) void rt_awsm(float* __restrict__ aw, int groups)
{
  int gidx = blockIdx.x * 256 + threadIdx.x;
  if (gidx >= groups) return;
  float* p = aw + (size_t)gidx * 12;
  float e[12]; float m = -1e30f;
#pragma unroll
  for (int i = 0; i < 12; i++) { e[i] = p[i]; m = fmaxf(m, e[i]); }
  float s = 0.f;
#pragma unroll
  for (int i = 0; i < 12; i++) { e[i] = __expf(e[i] - m); s += e[i]; }
  float inv = 1.f / s;
#pragma unroll
  for (int i = 0; i < 12; i++) p[i] = e[i] * inv;
}

// ---------- deformable sampling ----------
__device__ inline float rt_samp(const ushort16* vl, int xi, int yi, int Wl) {
  if (xi < 0 || xi >= Wl || yi < 0 || yi >= Wl) return 0.f;
  return bf2f(vl[(size_t)(yi * Wl + xi) * HD_]);
}

__global__ __launch_bounds__(256) void rt_deform(
    const ushort16* __restrict__ value,   // [B][H][S][HD] bf16
    const float* __restrict__ off,        // [B][NQ][H][L][P][2]
    const float* __restrict__ aw,         // [B][NQ][H][12]
    const float* __restrict__ ref,        // [B][NQ][1][4]
    float* __restrict__ O)                // [B][NQ][D]
{
  int gid = blockIdx.x * 256 + threadIdx.x;
  int hd  = gid & 31;
  int bqh = gid >> 5;
  int h   = bqh & 7;
  int bq  = bqh >> 3;
  int b   = bq / NQ_;
  const float* rp = ref + (size_t)bq * 4;
  float rx = rp[0], ry = rp[1];
  float rw = rp[2] * 0.125f, rh = rp[3] * 0.125f;
  const float* op = off + (size_t)bqh * 24;
  const float* ap = aw  + (size_t)bqh * 12;
  const ushort16* vb = value + ((size_t)b * H_ + h) * (size_t)S_ * HD_ + hd;
  float acc = 0.f;
  const int starts[3] = {0, 6400, 8000};
  const int dims[3]   = {80, 40, 20};
#pragma unroll
  for (int l = 0; l < L_; l++) {
    const int Wl = dims[l];
    const ushort16* vl = vb + (size_t)starts[l] * HD_;
#pragma unroll
    for (int p = 0; p < P_; p++) {
      int ip = l * P_ + p;
      float w = ap[ip];
      float x = (rx + op[ip*2+0] * rw) * Wl - 0.5f;
      float y = (ry + op[ip*2+1] * rh) * Wl - 0.5f;
      float x0f = floorf(x), y0f = floorf(y);
      int   x0 = (int)x0f,  y0 = (int)y0f;
      float wx1 = x - x0f, wy1 = y - y0f;
      float wx0 = 1.f - wx1, wy0 = 1.f - wy1;
      float v00 = rt_samp(vl, x0,     y0,     Wl);
      float v10 = rt_samp(vl, x0 + 1, y0,     Wl);
      float v01 = rt_samp(vl, x0,     y0 + 1, Wl);
      float v11 = rt_samp(vl, x0 + 1, y0 + 1, Wl);
      acc += w * (v00 * wx0 * wy0 + v10 * wx1 * wy0 + v01 * wx0 * wy1 + v11 * wx1 * wy1);
    }
  }
  O[gid] = acc;
}

// ---------- launch ----------
extern "C" void kernel_launch(void* const* d_in, const int* in_sizes, int n_in,
                              void* d_out, int out_size, void* d_ws, size_t ws_size,
                              hipStream_t stream)
{
  const float* hs   = (const float*)d_in[0];
  const float* pos  = (const float*)d_in[1];
  const float* ref  = (const float*)d_in[2];
  const float* ehs  = (const float*)d_in[3];
  const float* Wq   = (const float*)d_in[4];
  const float* Wk   = (const float*)d_in[5];
  const float* Wv   = (const float*)d_in[6];
  const float* Wo   = (const float*)d_in[7];
  const float* Woff = (const float*)d_in[8];
  const float* Waw  = (const float*)d_in[9];
  const float* Wval = (const float*)d_in[10];
  const float* Wout = (const float*)d_in[11];
  const float* W1   = (const float*)d_in[12];
  const float* W2   = (const float*)d_in[13];
  const float* bq   = (const float*)d_in[14];
  const float* bk   = (const float*)d_in[15];
  const float* bvv  = (const float*)d_in[16];
  const float* bo   = (const float*)d_in[17];
  const float* boff = (const float*)d_in[18];
  const float* baw  = (const float*)d_in[19];
  const float* bval = (const float*)d_in[20];
  const float* bout = (const float*)d_in[21];
  const float* b1   = (const float*)d_in[22];
  const float* b2   = (const float*)d_in[23];
  const float* ln1g = (const float*)d_in[24];
  const float* ln1b = (const float*)d_in[25];
  const float* ln2g = (const float*)d_in[26];
  const float* ln2b = (const float*)d_in[27];
  const float* ln3g = (const float*)d_in[28];
  const float* ln3b = (const float*)d_in[29];
  float* out = (float*)d_out;

  // workspace layout (float units)
  float* ws = (float*)d_ws;
  ushort16* value = (ushort16*)ws;               // 68,812,800 bf16 = 34,406,400 fl
  float* hp   = ws + 34406400;
  float* qb   = ws + 36864000;
  float* kb   = ws + 39321600;
  float* vb   = ws + 41779200;
  float* t0   = ws + 44236800;
  float* t1   = ws + 46694400;
  float* hs1  = ws + 49152000;
  float* hs2  = ws + 51609600;
  float* offb = ws + 54067200;
  float* awb  = ws + 55910400;
  float* ffn1 = ws + 56832000;                   // 9600*1024 -> ends 66,662,400
  // bf16 transposed weights (ushort units from here)
  ushort16* wbase = (ushort16*)(ws + 66662400);
  ushort16* WqT   = wbase;                 // 256*256
  ushort16* WkT   = WqT   + 65536;
  ushort16* WvT   = WkT   + 65536;
  ushort16* WoT   = WvT   + 65536;
  ushort16* WoffT = WoT   + 65536;         // 256(pad)*256
  ushort16* WawT  = WoffT + 65536;         // 128(pad)*256
  ushort16* WvalT = WawT  + 32768;
  ushort16* WoutT = WvalT + 65536;
  ushort16* W1T   = WoutT + 65536;         // 1024*256
  ushort16* W2T   = W1T   + 262144;        // 256*1024

  const float qscale = 0.17677669529663687f;     // HD^-0.5

  // 0) weight transposes (f32 [K,N] -> bf16 [Npad,K])
  rt_wt<<<dim3(8, 8),  256, 0, stream>>>(Wq,   WqT,   256, 256, 256);
  rt_wt<<<dim3(8, 8),  256, 0, stream>>>(Wk,   WkT,   256, 256, 256);
  rt_wt<<<dim3(8, 8),  256, 0, stream>>>(Wv,   WvT,   256, 256, 256);
  rt_wt<<<dim3(8, 8),  256, 0, stream>>>(Wo,   WoT,   256, 256, 256);
  rt_wt<<<dim3(8, 8),  256, 0, stream>>>(Woff, WoffT, 256, 192, 256);
  rt_wt<<<dim3(4, 8),  256, 0, stream>>>(Waw,  WawT,  256,  96, 128);
  rt_wt<<<dim3(8, 8),  256, 0, stream>>>(Wval, WvalT, 256, 256, 256);
  rt_wt<<<dim3(8, 8),  256, 0, stream>>>(Wout, WoutT, 256, 256, 256);
  rt_wt<<<dim3(32, 8), 256, 0, stream>>>(W1,   W1T,   256, 1024, 1024);
  rt_wt<<<dim3(8, 32), 256, 0, stream>>>(W2,   W2T,   1024, 256, 256);

  // 1) value projection -> bf16 scatter [B][H][S][HD]
  rt_mgemm<<<dim3(2, MV/GBM), 256, 0, stream>>>(ehs, WvalT, bval, nullptr, value,
                                                MV, D_, D_, 1.f, 2);
  // 2) hp = hs + pos
  rt_add<<<dim3(M1*D_/4/256), 256, 0, stream>>>(hs, pos, hp, M1*D_/4);
  // 3) q,k,v projections
  rt_mgemm<<<dim3(2, M1/GBM), 256, 0, stream>>>(hp, WqT, bq,  qb, nullptr, M1, D_, D_, qscale, 0);
  rt_mgemm<<<dim3(2, M1/GBM), 256, 0, stream>>>(hp, WkT, bk,  kb, nullptr, M1, D_, D_, 1.f, 0);
  rt_mgemm<<<dim3(2, M1/GBM), 256, 0, stream>>>(hs, WvT, bvv, vb, nullptr, M1, D_, D_, 1.f, 0);
  // 4) self-attention -> t0
  rt_attn<<<dim3(B_*H_), 320, 0, stream>>>(qb, kb, vb, t0);
  // 5) output proj -> t1 ; LN1 -> hs1
  rt_mgemm<<<dim3(2, M1/GBM), 256, 0, stream>>>(t0, WoT, bo, t1, nullptr, M1, D_, D_, 1.f, 0);
  rt_ln<<<dim3(M1/4), 256, 0, stream>>>(hs, t1, ln1g, ln1b, hs1, M1);
  // 6) hp = hs1 + pos ; off & aw projections ; aw softmax
  rt_add<<<dim3(M1*D_/4/256), 256, 0, stream>>>(hs1, pos, hp, M1*D_/4);
  rt_mgemm<<<dim3(2, M1/GBM), 256, 0, stream>>>(hp, WoffT, boff, offb, nullptr, M1, 192, D_, 1.f, 0);
  rt_mgemm<<<dim3(1, M1/GBM), 256, 0, stream>>>(hp, WawT,  baw,  awb,  nullptr, M1,  96, D_, 1.f, 0);
  rt_awsm<<<dim3(B_*NQ_*H_/256), 256, 0, stream>>>(awb, B_*NQ_*H_);
  // 7) deformable sampling -> t0 ; out proj -> t1 ; LN2 -> hs2
  rt_deform<<<dim3(M1*D_/256), 256, 0, stream>>>(value, offb, awb, ref, t0);
  rt_mgemm<<<dim3(2, M1/GBM), 256, 0, stream>>>(t0, WoutT, bout, t1, nullptr, M1, D_, D_, 1.f, 0);
  rt_ln<<<dim3(M1/4), 256, 0, stream>>>(hs1, t1, ln2g, ln2b, hs2, M1);
  // 8) FFN ; LN3 -> out
  rt_mgemm<<<dim3(8, M1/GBM), 256, 0, stream>>>(hs2, W1T, b1, ffn1, nullptr, M1, FFN_, D_, 1.f, 1);
  rt_mgemm<<<dim3(2, M1/GBM), 256, 0, stream>>>(ffn1, W2T, b2, t1, nullptr, M1, D_, FFN_, 1.f, 0);
  rt_ln<<<dim3(M1/4), 256, 0, stream>>>(hs2, t1, ln3g, ln3b, out, M1);
}

// Round 3
// 656.699 us; speedup vs baseline: 2.1315x; 1.2502x over previous
//
#include <hip/hip_runtime.h>
#include <hip/hip_bf16.h>

typedef unsigned int  uint32;
typedef unsigned short ushort16;
typedef __bf16 bfx8 __attribute__((ext_vector_type(8)));
typedef float  f32x4 __attribute__((ext_vector_type(4)));

#define B_   32
#define NQ_  300
#define D_   256
#define H_   8
#define HD_  32
#define L_   3
#define P_   4
#define S_   8400
#define FFN_ 1024
#define M1   (B_*NQ_)    // 9600
#define MV   (B_*S_)     // 268800
#define NQP  320         // padded query/key count (10 chunks of 32)
#define NQT  19          // 19 q-tiles of 16 cover 304 >= 300

// ---------- helpers ----------
__device__ inline ushort16 f2bf(float x) {
  uint32 u = __float_as_uint(x);
  uint32 r = u + 0x7fffu + ((u >> 16) & 1u);
  return (ushort16)(r >> 16);
}
__device__ inline float bf2f(ushort16 v) {
  return __uint_as_float(((uint32)v) << 16);
}

// ---------- elementwise add (float4) ----------
__global__ __launch_bounds__(256) void rt_add(const float* __restrict__ a,
                                              const float* __restrict__ b,
                                              float* __restrict__ o, int n4)
{
  int i = blockIdx.x * 256 + threadIdx.x;
  if (i < n4) {
    float4 x = ((const float4*)a)[i];
    float4 y = ((const float4*)b)[i];
    float4 z; z.x = x.x + y.x; z.y = x.y + y.y; z.z = x.z + y.z; z.w = x.w + y.w;
    ((float4*)o)[i] = z;
  }
}

// ---------- weight transpose+convert: W[K,N] f32 -> WT[Npad,K] bf16 (zero pad) ----------
__global__ __launch_bounds__(256) void rt_wt(const float* __restrict__ W,
                                             ushort16* __restrict__ WT,
                                             int K, int N, int Npad)
{
  __shared__ float t[32][33];
  int n0 = blockIdx.x * 32, k0 = blockIdx.y * 32;
  int c = threadIdx.x & 31, r = threadIdx.x >> 5;   // 32 x 8
#pragma unroll
  for (int i = 0; i < 4; i++) {
    int kk = k0 + r + i * 8;
    int nn = n0 + c;
    t[r + i * 8][c] = (nn < N) ? W[(size_t)kk * N + nn] : 0.f;
  }
  __syncthreads();
#pragma unroll
  for (int i = 0; i < 4; i++) {
    int nn = n0 + r + i * 8;
    int kk = k0 + c;
    if (nn < Npad) WT[(size_t)nn * K + kk] = f2bf(t[c][r + i * 8]);
  }
}

// ---------- MFMA bf16 GEMM: C[M,N] = A[M,K](f32) @ BT[Npad,K](bf16)^T + bias ----------
// mode 0: f32 C.  mode 1: f32 C + relu.  mode 2: bf16 scatter value[b][h][s][hd].
// mode 3: bf16 scatter head-layout [b][h][NQP][hd]  (q/k/v projections)
#define GBM 128
#define GBN 128
#define GBK 32
#define LDP 40

__global__ __launch_bounds__(256) void rt_mgemm(
    const float* __restrict__ A, const ushort16* __restrict__ BT,
    const float* __restrict__ bias, float* __restrict__ C,
    ushort16* __restrict__ Sc,
    int M, int N, int K, float scale, int mode)
{
  __shared__ __align__(16) ushort16 As[GBM][LDP];
  __shared__ __align__(16) ushort16 Bs[GBN][LDP];
  const int tid  = threadIdx.x;
  const int lane = tid & 63;
  const int w    = tid >> 6;
  const int wr   = (w >> 1) * 64;
  const int wc   = (w & 1) * 64;
  const int bm   = blockIdx.y * GBM;
  const int bn   = blockIdx.x * GBN;
  const int l15  = lane & 15;
  const int l4   = lane >> 4;

  f32x4 acc[4][4];
#pragma unroll
  for (int i = 0; i < 4; i++)
#pragma unroll
    for (int j = 0; j < 4; j++)
      acc[i][j] = (f32x4){0.f, 0.f, 0.f, 0.f};

  const int arow = tid >> 3, akc = tid & 7;
  const int brow = tid >> 2, bkc = tid & 3;

  for (int k0 = 0; k0 < K; k0 += GBK) {
#pragma unroll
    for (int i = 0; i < 4; i++) {
      int row = arow + i * 32;
      f32x4 v = *(const f32x4*)(A + (size_t)(bm + row) * K + k0 + akc * 4);
      uint2 u;
      u.x = (uint32)f2bf(v.x) | ((uint32)f2bf(v.y) << 16);
      u.y = (uint32)f2bf(v.z) | ((uint32)f2bf(v.w) << 16);
      *(uint2*)(&As[row][akc * 4]) = u;
    }
#pragma unroll
    for (int i = 0; i < 2; i++) {
      int row = brow + i * 64;
      uint4 v = *(const uint4*)(BT + (size_t)(bn + row) * K + k0 + bkc * 8);
      *(uint4*)(&Bs[row][bkc * 8]) = v;
    }
    __syncthreads();

    bfx8 af[4], bg[4];
#pragma unroll
    for (int mi = 0; mi < 4; mi++)
      af[mi] = *(const bfx8*)(&As[wr + mi * 16 + l15][l4 * 8]);
#pragma unroll
    for (int ni = 0; ni < 4; ni++)
      bg[ni] = *(const bfx8*)(&Bs[wc + ni * 16 + l15][l4 * 8]);
#pragma unroll
    for (int mi = 0; mi < 4; mi++)
#pragma unroll
      for (int ni = 0; ni < 4; ni++)
        acc[mi][ni] = __builtin_amdgcn_mfma_f32_16x16x32_bf16(af[mi], bg[ni], acc[mi][ni], 0, 0, 0);
    __syncthreads();
  }

#pragma unroll
  for (int mi = 0; mi < 4; mi++) {
#pragma unroll
    for (int ni = 0; ni < 4; ni++) {
      int col = bn + wc + ni * 16 + l15;
      if (col >= N) continue;
      float bv = bias[col];
#pragma unroll
      for (int r = 0; r < 4; r++) {
        int row = bm + wr + mi * 16 + l4 * 4 + r;
        float vv = (acc[mi][ni][r] + bv) * scale;
        if (mode == 1) vv = fmaxf(vv, 0.f);
        if (mode == 2) {
          int bb = row / S_, s = row - bb * S_;
          int hh = col >> 5, hd = col & 31;
          Sc[(((size_t)bb * H_ + hh) * S_ + s) * HD_ + hd] = f2bf(vv);
        } else if (mode == 3) {
          int bb = row / NQ_, q = row - bb * NQ_;
          int hh = col >> 5, hd = col & 31;
          Sc[(((size_t)bb * H_ + hh) * NQP + q) * HD_ + hd] = f2bf(vv);
        } else {
          C[(size_t)row * N + col] = vv;
        }
      }
    }
  }
}

// ---------- V transpose per (b,h): vh[bh][NQP][32] -> vt[bh][32][NQP] ----------
__global__ __launch_bounds__(256) void rt_vtr(const ushort16* __restrict__ vh,
                                              ushort16* __restrict__ vt)
{
  __shared__ ushort16 t[64][33];
  int bh = blockIdx.x;
  const ushort16* src = vh + (size_t)bh * NQP * HD_;
  ushort16* dst = vt + (size_t)bh * HD_ * NQP;
  int tid = threadIdx.x;
  int lrow = tid >> 2, lc8 = (tid & 3) * 8;
  int ohd = tid >> 3, oq8 = (tid & 7) * 8;
  for (int r0 = 0; r0 < NQP; r0 += 64) {
    uint4 v = *(const uint4*)(src + (size_t)(r0 + lrow) * HD_ + lc8);
    ushort16* tp = &t[lrow][lc8];
    tp[0] = (ushort16)(v.x & 0xffff); tp[1] = (ushort16)(v.x >> 16);
    tp[2] = (ushort16)(v.y & 0xffff); tp[3] = (ushort16)(v.y >> 16);
    tp[4] = (ushort16)(v.z & 0xffff); tp[5] = (ushort16)(v.z >> 16);
    tp[6] = (ushort16)(v.w & 0xffff); tp[7] = (ushort16)(v.w >> 16);
    __syncthreads();
    uint4 o;
    o.x = (uint32)t[oq8 + 0][ohd] | ((uint32)t[oq8 + 1][ohd] << 16);
    o.y = (uint32)t[oq8 + 2][ohd] | ((uint32)t[oq8 + 3][ohd] << 16);
    o.z = (uint32)t[oq8 + 4][ohd] | ((uint32)t[oq8 + 5][ohd] << 16);
    o.w = (uint32)t[oq8 + 6][ohd] | ((uint32)t[oq8 + 7][ohd] << 16);
    *(uint4*)(dst + (size_t)ohd * NQP + r0 + oq8) = o;
    __syncthreads();
  }
}

// ---------- MFMA flash self-attention ----------
// One wave per (b,h,qtile16). S^T = mfma(K,Q); online softmax; O^T = mfma(VT,P).
__global__ __launch_bounds__(256) void rt_fattn(
    const ushort16* __restrict__ qh, const ushort16* __restrict__ kh,
    const ushort16* __restrict__ vt, float* __restrict__ O)
{
  int gw  = blockIdx.x * 4 + (threadIdx.x >> 6);   // global wave id
  int bh  = gw / NQT, qt = gw - bh * NQT;
  int b   = bh >> 3, h = bh & 7;
  int lane = threadIdx.x & 63;
  int l15 = lane & 15, l4 = lane >> 4;
  int kb4 = l4 * 4;
  const ushort16* Qb = qh + (size_t)bh * NQP * HD_;
  const ushort16* Kb = kh + (size_t)bh * NQP * HD_;
  const ushort16* Vb = vt + (size_t)bh * HD_ * NQP;
  int q = qt * 16 + l15;

  bfx8 bgQ = *(const bfx8*)(const void*)(Qb + (size_t)q * HD_ + l4 * 8);
  f32x4 o0 = {0.f,0.f,0.f,0.f}, o1 = {0.f,0.f,0.f,0.f};
  float m = -1e30f, ssum = 0.f;

  for (int k0 = 0; k0 < NQP; k0 += 32) {
    bfx8 afk0 = *(const bfx8*)(const void*)(Kb + (size_t)(k0 + l15) * HD_ + l4 * 8);
    bfx8 afk1 = *(const bfx8*)(const void*)(Kb + (size_t)(k0 + 16 + l15) * HD_ + l4 * 8);
    f32x4 z = {0.f,0.f,0.f,0.f};
    f32x4 s0 = __builtin_amdgcn_mfma_f32_16x16x32_bf16(afk0, bgQ, z, 0, 0, 0);
    f32x4 s1 = __builtin_amdgcn_mfma_f32_16x16x32_bf16(afk1, bgQ, z, 0, 0, 0);
    int ka = k0 + kb4, kbb = k0 + 16 + kb4;
#pragma unroll
    for (int r = 0; r < 4; r++) {
      if (ka  + r >= NQ_) s0[r] = -1e30f;
      if (kbb + r >= NQ_) s1[r] = -1e30f;
    }
    float cm = fmaxf(fmaxf(fmaxf(s0[0], s0[1]), fmaxf(s0[2], s0[3])),
                     fmaxf(fmaxf(s1[0], s1[1]), fmaxf(s1[2], s1[3])));
    cm = fmaxf(cm, __shfl_xor(cm, 16));
    cm = fmaxf(cm, __shfl_xor(cm, 32));
    float nm = fmaxf(m, cm);
    float sc = __expf(m - nm);
    m = nm;
    f32x4 p0, p1;
#pragma unroll
    for (int r = 0; r < 4; r++) { p0[r] = __expf(s0[r] - m); p1[r] = __expf(s1[r] - m); }
    float ls = (p0[0]+p0[1]+p0[2]+p0[3]) + (p1[0]+p1[1]+p1[2]+p1[3]);
    ls += __shfl_xor(ls, 16);
    ls += __shfl_xor(ls, 32);
    ssum = ssum * sc + ls;

    uint32 t0w0, t0w1, t1w0, t1w1;
    asm("v_cvt_pk_bf16_f32 %0, %1, %2" : "=v"(t0w0) : "v"(p0[0]), "v"(p0[1]));
    asm("v_cvt_pk_bf16_f32 %0, %1, %2" : "=v"(t0w1) : "v"(p0[2]), "v"(p0[3]));
    asm("v_cvt_pk_bf16_f32 %0, %1, %2" : "=v"(t1w0) : "v"(p1[0]), "v"(p1[1]));
    asm("v_cvt_pk_bf16_f32 %0, %1, %2" : "=v"(t1w1) : "v"(p1[2]), "v"(p1[3]));
    int srcA = l15 + 32 * (l4 & 1);
    int srcB = srcA + 16;
    uint32 a00 = __shfl((int)t0w0, srcA), a01 = __shfl((int)t0w1, srcA);
    uint32 b00 = __shfl((int)t0w0, srcB), b01 = __shfl((int)t0w1, srcB);
    uint32 a10 = __shfl((int)t1w0, srcA), a11 = __shfl((int)t1w1, srcA);
    uint32 b10 = __shfl((int)t1w0, srcB), b11 = __shfl((int)t1w1, srcB);
    bool hi = (l4 >= 2);
    uint4 pw;
    pw.x = hi ? a10 : a00;
    pw.y = hi ? a11 : a01;
    pw.z = hi ? b10 : b00;
    pw.w = hi ? b11 : b01;
    bfx8 bgP = __builtin_bit_cast(bfx8, pw);

    bfx8 afv0 = *(const bfx8*)(const void*)(Vb + (size_t)l15 * NQP + k0 + l4 * 8);
    bfx8 afv1 = *(const bfx8*)(const void*)(Vb + (size_t)(16 + l15) * NQP + k0 + l4 * 8);
#pragma unroll
    for (int r = 0; r < 4; r++) { o0[r] *= sc; o1[r] *= sc; }
    o0 = __builtin_amdgcn_mfma_f32_16x16x32_bf16(afv0, bgP, o0, 0, 0, 0);
    o1 = __builtin_amdgcn_mfma_f32_16x16x32_bf16(afv1, bgP, o1, 0, 0, 0);
  }

  if (q < NQ_) {
    float inv = 1.f / ssum;
    float* op = O + ((size_t)(b * NQ_ + q)) * D_ + h * HD_ + kb4;
    f32x4 r0, r1;
#pragma unroll
    for (int r = 0; r < 4; r++) { r0[r] = o0[r] * inv; r1[r] = o1[r] * inv; }
    *(f32x4*)op = r0;
    *(f32x4*)(op + 16) = r1;
  }
}

// ---------- LayerNorm ----------
__global__ __launch_bounds__(256) void rt_ln(
    const float* __restrict__ X, const float* __restrict__ R,
    const float* __restrict__ g, const float* __restrict__ be,
    float* __restrict__ O, int rows)
{
  int row = blockIdx.x * 4 + (threadIdx.x >> 6);
  int lane = threadIdx.x & 63;
  if (row >= rows) return;
  size_t base = (size_t)row * D_ + lane * 4;
  float4 x = *(const float4*)(X + base);
  float4 r = *(const float4*)(R + base);
  float v0 = x.x + r.x, v1 = x.y + r.y, v2 = x.z + r.z, v3 = x.w + r.w;
  float s = v0 + v1 + v2 + v3;
  float sq = v0*v0 + v1*v1 + v2*v2 + v3*v3;
#pragma unroll
  for (int o = 32; o >= 1; o >>= 1) { s += __shfl_xor(s, o); sq += __shfl_xor(sq, o); }
  float mean = s * (1.f / D_);
  float var  = sq * (1.f / D_) - mean * mean;
  float inv  = 1.f / sqrtf(var + 1e-5f);
  int c = lane * 4;
  float4 gv = *(const float4*)(g + c);
  float4 bv = *(const float4*)(be + c);
  float4 o4;
  o4.x = (v0 - mean) * inv * gv.x + bv.x;
  o4.y = (v1 - mean) * inv * gv.y + bv.y;
  o4.z = (v2 - mean) * inv * gv.z + bv.z;
  o4.w = (v3 - mean) * inv * gv.w + bv.w;
  *(float4*)(O + base) = o4;
}

// ---------- attention-weight softmax ----------
__global__ __launch_bounds__(256) void rt_awsm(float* __restrict__ aw, int groups)
{
  int gidx = blockIdx.x * 256 + threadIdx.x;
  if (gidx >= groups) return;
  float* p = aw + (size_t)gidx * 12;
  float e[12]; float m = -1e30f;
#pragma unroll
  for (int i = 0; i < 12; i++) { e[i] = p[i]; m = fmaxf(m, e[i]); }
  float s = 0.f;
#pragma unroll
  for (int i = 0; i < 12; i++) { e[i] = __expf(e[i] - m); s += e[i]; }
  float inv = 1.f / s;
#pragma unroll
  for (int i = 0; i < 12; i++) p[i] = e[i] * inv;
}

// ---------- deformable sampling ----------
__device__ inline float rt_samp(const ushort16* vl, int xi, int yi, int Wl) {
  if (xi < 0 || xi >= Wl || yi < 0 || yi >= Wl) return 0.f;
  return bf2f(vl[(size_t)(yi * Wl + xi) * HD_]);
}

__global__ __launch_bounds__(256) void rt_deform(
    const ushort16* __restrict__ value,
    const float* __restrict__ off,
    const float* __restrict__ aw,
    const float* __restrict__ ref,
    float* __restrict__ O)
{
  int gid = blockIdx.x * 256 + threadIdx.x;
  int hd  = gid & 31;
  int bqh = gid >> 5;
  int h   = bqh & 7;
  int bq  = bqh >> 3;
  int b   = bq / NQ_;
  const float* rp = ref + (size_t)bq * 4;
  float rx = rp[0], ry = rp[1];
  float rw = rp[2] * 0.125f, rh = rp[3] * 0.125f;
  const float* op = off + (size_t)bqh * 24;
  const float* ap = aw  + (size_t)bqh * 12;
  const ushort16* vb = value + ((size_t)b * H_ + h) * (size_t)S_ * HD_ + hd;
  float acc = 0.f;
  const int starts[3] = {0, 6400, 8000};
  const int dims[3]   = {80, 40, 20};
#pragma unroll
  for (int l = 0; l < L_; l++) {
    const int Wl = dims[l];
    const ushort16* vl = vb + (size_t)starts[l] * HD_;
#pragma unroll
    for (int p = 0; p < P_; p++) {
      int ip = l * P_ + p;
      float w = ap[ip];
      float x = (rx + op[ip*2+0] * rw) * Wl - 0.5f;
      float y = (ry + op[ip*2+1] * rh) * Wl - 0.5f;
      float x0f = floorf(x), y0f = floorf(y);
      int   x0 = (int)x0f,  y0 = (int)y0f;
      float wx1 = x - x0f, wy1 = y - y0f;
      float wx0 = 1.f - wx1, wy0 = 1.f - wy1;
      float v00 = rt_samp(vl, x0,     y0,     Wl);
      float v10 = rt_samp(vl, x0 + 1, y0,     Wl);
      float v01 = rt_samp(vl, x0,     y0 + 1, Wl);
      float v11 = rt_samp(vl, x0 + 1, y0 + 1, Wl);
      acc += w * (v00 * wx0 * wy0 + v10 * wx1 * wy0 + v01 * wx0 * wy1 + v11 * wx1 * wy1);
    }
  }
  O[gid] = acc;
}

// ---------- launch ----------
extern "C" void kernel_launch(void* const* d_in, const int* in_sizes, int n_in,
                              void* d_out, int out_size, void* d_ws, size_t ws_size,
                              hipStream_t stream)
{
  const float* hs   = (const float*)d_in[0];
  const float* pos  = (const float*)d_in[1];
  const float* ref  = (const float*)d_in[2];
  const float* ehs  = (const float*)d_in[3];
  const float* Wq   = (const float*)d_in[4];
  const float* Wk   = (const float*)d_in[5];
  const float* Wv   = (const float*)d_in[6];
  const float* Wo   = (const float*)d_in[7];
  const float* Woff = (const float*)d_in[8];
  const float* Waw  = (const float*)d_in[9];
  const float* Wval = (const float*)d_in[10];
  const float* Wout = (const float*)d_in[11];
  const float* W1   = (const float*)d_in[12];
  const float* W2   = (const float*)d_in[13];
  const float* bq   = (const float*)d_in[14];
  const float* bk   = (const float*)d_in[15];
  const float* bvv  = (const float*)d_in[16];
  const float* bo   = (const float*)d_in[17];
  const float* boff = (const float*)d_in[18];
  const float* baw  = (const float*)d_in[19];
  const float* bval = (const float*)d_in[20];
  const float* bout = (const float*)d_in[21];
  const float* b1   = (const float*)d_in[22];
  const float* b2   = (const float*)d_in[23];
  const float* ln1g = (const float*)d_in[24];
  const float* ln1b = (const float*)d_in[25];
  const float* ln2g = (const float*)d_in[26];
  const float* ln2b = (const float*)d_in[27];
  const float* ln3g = (const float*)d_in[28];
  const float* ln3b = (const float*)d_in[29];
  float* out = (float*)d_out;

  // workspace layout (float units)
  float* ws = (float*)d_ws;
  ushort16* value = (ushort16*)ws;                       // [B][H][S][HD] bf16
  float* hp   = ws + 34406400;
  float* t0   = ws + 36864000;
  float* t1   = ws + 39321600;
  float* hs1  = ws + 41779200;
  float* hs2  = ws + 44236800;
  float* offb = ws + 46694400;
  float* awb  = ws + 48537600;
  float* ffn1 = ws + 49459200;                           // ends 59,289,600
  ushort16* qh = (ushort16*)(ws + 59289600);             // [256][320][32] bf16
  ushort16* kh = (ushort16*)(ws + 60600320);
  ushort16* vh = (ushort16*)(ws + 61911040);
  ushort16* vt = (ushort16*)(ws + 63221760);             // [256][32][320]
  ushort16* wbase = (ushort16*)(ws + 64532480);
  ushort16* WqT   = wbase;
  ushort16* WkT   = WqT   + 65536;
  ushort16* WvT   = WkT   + 65536;
  ushort16* WoT   = WvT   + 65536;
  ushort16* WoffT = WoT   + 65536;
  ushort16* WawT  = WoffT + 65536;
  ushort16* WvalT = WawT  + 32768;
  ushort16* WoutT = WvalT + 65536;
  ushort16* W1T   = WoutT + 65536;
  ushort16* W2T   = W1T   + 262144;

  const float qscale = 0.17677669529663687f;

  // 0) weight transposes
  rt_wt<<<dim3(8, 8),  256, 0, stream>>>(Wq,   WqT,   256, 256, 256);
  rt_wt<<<dim3(8, 8),  256, 0, stream>>>(Wk,   WkT,   256, 256, 256);
  rt_wt<<<dim3(8, 8),  256, 0, stream>>>(Wv,   WvT,   256, 256, 256);
  rt_wt<<<dim3(8, 8),  256, 0, stream>>>(Wo,   WoT,   256, 256, 256);
  rt_wt<<<dim3(8, 8),  256, 0, stream>>>(Woff, WoffT, 256, 192, 256);
  rt_wt<<<dim3(4, 8),  256, 0, stream>>>(Waw,  WawT,  256,  96, 128);
  rt_wt<<<dim3(8, 8),  256, 0, stream>>>(Wval, WvalT, 256, 256, 256);
  rt_wt<<<dim3(8, 8),  256, 0, stream>>>(Wout, WoutT, 256, 256, 256);
  rt_wt<<<dim3(32, 8), 256, 0, stream>>>(W1,   W1T,   256, 1024, 1024);
  rt_wt<<<dim3(8, 32), 256, 0, stream>>>(W2,   W2T,   1024, 256, 256);

  // 1) value projection -> bf16 scatter
  rt_mgemm<<<dim3(2, MV/GBM), 256, 0, stream>>>(ehs, WvalT, bval, nullptr, value,
                                                MV, D_, D_, 1.f, 2);
  // 2) hp = hs + pos
  rt_add<<<dim3(M1*D_/4/256), 256, 0, stream>>>(hs, pos, hp, M1*D_/4);
  // 3) q,k,v projections -> head-separated bf16
  rt_mgemm<<<dim3(2, M1/GBM), 256, 0, stream>>>(hp, WqT, bq,  nullptr, qh, M1, D_, D_, qscale, 3);
  rt_mgemm<<<dim3(2, M1/GBM), 256, 0, stream>>>(hp, WkT, bk,  nullptr, kh, M1, D_, D_, 1.f, 3);
  rt_mgemm<<<dim3(2, M1/GBM), 256, 0, stream>>>(hs, WvT, bvv, nullptr, vh, M1, D_, D_, 1.f, 3);
  rt_vtr<<<dim3(B_*H_), 256, 0, stream>>>(vh, vt);
  // 4) MFMA flash self-attention -> t0
  rt_fattn<<<dim3(B_*H_*NQT/4), 256, 0, stream>>>(qh, kh, vt, t0);
  // 5) output proj -> t1 ; LN1 -> hs1
  rt_mgemm<<<dim3(2, M1/GBM), 256, 0, stream>>>(t0, WoT, bo, t1, nullptr, M1, D_, D_, 1.f, 0);
  rt_ln<<<dim3(M1/4), 256, 0, stream>>>(hs, t1, ln1g, ln1b, hs1, M1);
  // 6) hp = hs1 + pos ; off & aw projections ; aw softmax
  rt_add<<<dim3(M1*D_/4/256), 256, 0, stream>>>(hs1, pos, hp, M1*D_/4);
  rt_mgemm<<<dim3(2, M1/GBM), 256, 0, stream>>>(hp, WoffT, boff, offb, nullptr, M1, 192, D_, 1.f, 0);
  rt_mgemm<<<dim3(1, M1/GBM), 256, 0, stream>>>(hp, WawT,  baw,  awb,  nullptr, M1,  96, D_, 1.f, 0);
  rt_awsm<<<dim3(B_*NQ_*H_/256), 256, 0, stream>>>(awb, B_*NQ_*H_);
  // 7) deformable sampling -> t0 ; out proj -> t1 ; LN2 -> hs2
  rt_deform<<<dim3(M1*D_/256), 256, 0, stream>>>(value, offb, awb, ref, t0);
  rt_mgemm<<<dim3(2, M1/GBM), 256, 0, stream>>>(t0, WoutT, bout, t1, nullptr, M1, D_, D_, 1.f, 0);
  rt_ln<<<dim3(M1/4), 256, 0, stream>>>(hs1, t1, ln2g, ln2b, hs2, M1);
  // 8) FFN ; LN3 -> out
  rt_mgemm<<<dim3(8, M1/GBM), 256, 0, stream>>>(hs2, W1T, b1, ffn1, nullptr, M1, FFN_, D_, 1.f, 1);
  rt_mgemm<<<dim3(2, M1/GBM), 256, 0, stream>>>(ffn1, W2T, b2, t1, nullptr, M1, D_, FFN_, 1.f, 0);
  rt_ln<<<dim3(M1/4), 256, 0, stream>>>(hs2, t1, ln3g, ln3b, out, M1);
}

// Round 4
// 500.551 us; speedup vs baseline: 2.7965x; 1.3120x over previous
//
#include <hip/hip_runtime.h>
#include <hip/hip_bf16.h>

typedef unsigned int  uint32;
typedef unsigned short ushort16;
typedef __bf16 bfx8 __attribute__((ext_vector_type(8)));
typedef float  f32x4 __attribute__((ext_vector_type(4)));

#define B_   32
#define NQ_  300
#define D_   256
#define H_   8
#define HD_  32
#define L_   3
#define P_   4
#define S_   8400
#define FFN_ 1024
#define M1   (B_*NQ_)    // 9600
#define MV   (B_*S_)     // 268800
#define NQP  320         // padded query/key count
#define NQT  19          // 19 q-tiles of 16 cover 304 >= 300

// ---------- helpers ----------
__device__ inline ushort16 f2bf(float x) {
  uint32 u = __float_as_uint(x);
  uint32 r = u + 0x7fffu + ((u >> 16) & 1u);
  return (ushort16)(r >> 16);
}
__device__ inline float bf2f(ushort16 v) {
  return __uint_as_float(((uint32)v) << 16);
}

// ---------- elementwise add (float4) ----------
__global__ __launch_bounds__(256) void rt_add(const float* __restrict__ a,
                                              const float* __restrict__ b,
                                              float* __restrict__ o, int n4)
{
  int i = blockIdx.x * 256 + threadIdx.x;
  if (i < n4) {
    float4 x = ((const float4*)a)[i];
    float4 y = ((const float4*)b)[i];
    float4 z; z.x = x.x + y.x; z.y = x.y + y.y; z.z = x.z + y.z; z.w = x.w + y.w;
    ((float4*)o)[i] = z;
  }
}

// ---------- weight transpose+convert: W[K,N] f32 -> WT[Npad,K] bf16 (zero pad) ----------
__global__ __launch_bounds__(256) void rt_wt(const float* __restrict__ W,
                                             ushort16* __restrict__ WT,
                                             int K, int N, int Npad)
{
  __shared__ float t[32][33];
  int n0 = blockIdx.x * 32, k0 = blockIdx.y * 32;
  int c = threadIdx.x & 31, r = threadIdx.x >> 5;
#pragma unroll
  for (int i = 0; i < 4; i++) {
    int kk = k0 + r + i * 8;
    int nn = n0 + c;
    t[r + i * 8][c] = (nn < N) ? W[(size_t)kk * N + nn] : 0.f;
  }
  __syncthreads();
#pragma unroll
  for (int i = 0; i < 4; i++) {
    int nn = n0 + r + i * 8;
    int kk = k0 + c;
    if (nn < Npad) WT[(size_t)nn * K + kk] = f2bf(t[c][r + i * 8]);
  }
}

// ---------- MFMA bf16 GEMM ----------
// mode 0: f32 C.  mode 1: f32 C + relu.  mode 2: bf16 scatter value[b][h][s][hd].
// mode 3: bf16 scatter head-layout [b][h][NQP][hd]
#define GBM 128
#define GBN 128
#define GBK 32
#define LDP 40

__global__ __launch_bounds__(256) void rt_mgemm(
    const float* __restrict__ A, const ushort16* __restrict__ BT,
    const float* __restrict__ bias, float* __restrict__ C,
    ushort16* __restrict__ Sc,
    int M, int N, int K, float scale, int mode)
{
  __shared__ __align__(16) ushort16 As[GBM][LDP];
  __shared__ __align__(16) ushort16 Bs[GBN][LDP];
  const int tid  = threadIdx.x;
  const int lane = tid & 63;
  const int w    = tid >> 6;
  const int wr   = (w >> 1) * 64;
  const int wc   = (w & 1) * 64;
  const int bm   = blockIdx.y * GBM;
  const int bn   = blockIdx.x * GBN;
  const int l15  = lane & 15;
  const int l4   = lane >> 4;

  f32x4 acc[4][4];
#pragma unroll
  for (int i = 0; i < 4; i++)
#pragma unroll
    for (int j = 0; j < 4; j++)
      acc[i][j] = (f32x4){0.f, 0.f, 0.f, 0.f};

  const int arow = tid >> 3, akc = tid & 7;
  const int brow = tid >> 2, bkc = tid & 3;

  for (int k0 = 0; k0 < K; k0 += GBK) {
#pragma unroll
    for (int i = 0; i < 4; i++) {
      int row = arow + i * 32;
      f32x4 v = *(const f32x4*)(A + (size_t)(bm + row) * K + k0 + akc * 4);
      uint2 u;
      u.x = (uint32)f2bf(v.x) | ((uint32)f2bf(v.y) << 16);
      u.y = (uint32)f2bf(v.z) | ((uint32)f2bf(v.w) << 16);
      *(uint2*)(&As[row][akc * 4]) = u;
    }
#pragma unroll
    for (int i = 0; i < 2; i++) {
      int row = brow + i * 64;
      uint4 v = *(const uint4*)(BT + (size_t)(bn + row) * K + k0 + bkc * 8);
      *(uint4*)(&Bs[row][bkc * 8]) = v;
    }
    __syncthreads();

    bfx8 af[4], bg[4];
#pragma unroll
    for (int mi = 0; mi < 4; mi++)
      af[mi] = *(const bfx8*)(&As[wr + mi * 16 + l15][l4 * 8]);
#pragma unroll
    for (int ni = 0; ni < 4; ni++)
      bg[ni] = *(const bfx8*)(&Bs[wc + ni * 16 + l15][l4 * 8]);
#pragma unroll
    for (int mi = 0; mi < 4; mi++)
#pragma unroll
      for (int ni = 0; ni < 4; ni++)
        acc[mi][ni] = __builtin_amdgcn_mfma_f32_16x16x32_bf16(af[mi], bg[ni], acc[mi][ni], 0, 0, 0);
    __syncthreads();
  }

#pragma unroll
  for (int mi = 0; mi < 4; mi++) {
#pragma unroll
    for (int ni = 0; ni < 4; ni++) {
      int col = bn + wc + ni * 16 + l15;
      if (col >= N) continue;
      float bv = bias[col];
#pragma unroll
      for (int r = 0; r < 4; r++) {
        int row = bm + wr + mi * 16 + l4 * 4 + r;
        float vv = (acc[mi][ni][r] + bv) * scale;
        if (mode == 1) vv = fmaxf(vv, 0.f);
        if (mode == 2) {
          int bb = row / S_, s = row - bb * S_;
          int hh = col >> 5, hd = col & 31;
          Sc[(((size_t)bb * H_ + hh) * S_ + s) * HD_ + hd] = f2bf(vv);
        } else if (mode == 3) {
          int bb = row / NQ_, q = row - bb * NQ_;
          int hh = col >> 5, hd = col & 31;
          Sc[(((size_t)bb * H_ + hh) * NQP + q) * HD_ + hd] = f2bf(vv);
        } else {
          C[(size_t)row * N + col] = vv;
        }
      }
    }
  }
}

// ---------- V transpose per (b,h) ----------
__global__ __launch_bounds__(256) void rt_vtr(const ushort16* __restrict__ vh,
                                              ushort16* __restrict__ vt)
{
  __shared__ ushort16 t[64][33];
  int bh = blockIdx.x;
  const ushort16* src = vh + (size_t)bh * NQP * HD_;
  ushort16* dst = vt + (size_t)bh * HD_ * NQP;
  int tid = threadIdx.x;
  int lrow = tid >> 2, lc8 = (tid & 3) * 8;
  int ohd = tid >> 3, oq8 = (tid & 7) * 8;
  for (int r0 = 0; r0 < NQP; r0 += 64) {
    uint4 v = *(const uint4*)(src + (size_t)(r0 + lrow) * HD_ + lc8);
    ushort16* tp = &t[lrow][lc8];
    tp[0] = (ushort16)(v.x & 0xffff); tp[1] = (ushort16)(v.x >> 16);
    tp[2] = (ushort16)(v.y & 0xffff); tp[3] = (ushort16)(v.y >> 16);
    tp[4] = (ushort16)(v.z & 0xffff); tp[5] = (ushort16)(v.z >> 16);
    tp[6] = (ushort16)(v.w & 0xffff); tp[7] = (ushort16)(v.w >> 16);
    __syncthreads();
    uint4 o;
    o.x = (uint32)t[oq8 + 0][ohd] | ((uint32)t[oq8 + 1][ohd] << 16);
    o.y = (uint32)t[oq8 + 2][ohd] | ((uint32)t[oq8 + 3][ohd] << 16);
    o.z = (uint32)t[oq8 + 4][ohd] | ((uint32)t[oq8 + 5][ohd] << 16);
    o.w = (uint32)t[oq8 + 6][ohd] | ((uint32)t[oq8 + 7][ohd] << 16);
    *(uint4*)(dst + (size_t)ohd * NQP + r0 + oq8) = o;
    __syncthreads();
  }
}

// ---------- MFMA flash self-attention ----------
__global__ __launch_bounds__(256) void rt_fattn(
    const ushort16* __restrict__ qh, const ushort16* __restrict__ kh,
    const ushort16* __restrict__ vt, float* __restrict__ O)
{
  int gw  = blockIdx.x * 4 + (threadIdx.x >> 6);
  int bh  = gw / NQT, qt = gw - bh * NQT;
  int b   = bh >> 3, h = bh & 7;
  int lane = threadIdx.x & 63;
  int l15 = lane & 15, l4 = lane >> 4;
  int kb4 = l4 * 4;
  const ushort16* Qb = qh + (size_t)bh * NQP * HD_;
  const ushort16* Kb = kh + (size_t)bh * NQP * HD_;
  const ushort16* Vb = vt + (size_t)bh * HD_ * NQP;
  int q = qt * 16 + l15;

  bfx8 bgQ = *(const bfx8*)(const void*)(Qb + (size_t)q * HD_ + l4 * 8);
  f32x4 o0 = {0.f,0.f,0.f,0.f}, o1 = {0.f,0.f,0.f,0.f};
  float m = -1e30f, ssum = 0.f;

  for (int k0 = 0; k0 < NQP; k0 += 32) {
    bfx8 afk0 = *(const bfx8*)(const void*)(Kb + (size_t)(k0 + l15) * HD_ + l4 * 8);
    bfx8 afk1 = *(const bfx8*)(const void*)(Kb + (size_t)(k0 + 16 + l15) * HD_ + l4 * 8);
    f32x4 z = {0.f,0.f,0.f,0.f};
    f32x4 s0 = __builtin_amdgcn_mfma_f32_16x16x32_bf16(afk0, bgQ, z, 0, 0, 0);
    f32x4 s1 = __builtin_amdgcn_mfma_f32_16x16x32_bf16(afk1, bgQ, z, 0, 0, 0);
    int ka = k0 + kb4, kbb = k0 + 16 + kb4;
#pragma unroll
    for (int r = 0; r < 4; r++) {
      if (ka  + r >= NQ_) s0[r] = -1e30f;
      if (kbb + r >= NQ_) s1[r] = -1e30f;
    }
    float cm = fmaxf(fmaxf(fmaxf(s0[0], s0[1]), fmaxf(s0[2], s0[3])),
                     fmaxf(fmaxf(s1[0], s1[1]), fmaxf(s1[2], s1[3])));
    cm = fmaxf(cm, __shfl_xor(cm, 16));
    cm = fmaxf(cm, __shfl_xor(cm, 32));
    float nm = fmaxf(m, cm);
    float sc = __expf(m - nm);
    m = nm;
    f32x4 p0, p1;
#pragma unroll
    for (int r = 0; r < 4; r++) { p0[r] = __expf(s0[r] - m); p1[r] = __expf(s1[r] - m); }
    float ls = (p0[0]+p0[1]+p0[2]+p0[3]) + (p1[0]+p1[1]+p1[2]+p1[3]);
    ls += __shfl_xor(ls, 16);
    ls += __shfl_xor(ls, 32);
    ssum = ssum * sc + ls;

    uint32 t0w0, t0w1, t1w0, t1w1;
    asm("v_cvt_pk_bf16_f32 %0, %1, %2" : "=v"(t0w0) : "v"(p0[0]), "v"(p0[1]));
    asm("v_cvt_pk_bf16_f32 %0, %1, %2" : "=v"(t0w1) : "v"(p0[2]), "v"(p0[3]));
    asm("v_cvt_pk_bf16_f32 %0, %1, %2" : "=v"(t1w0) : "v"(p1[0]), "v"(p1[1]));
    asm("v_cvt_pk_bf16_f32 %0, %1, %2" : "=v"(t1w1) : "v"(p1[2]), "v"(p1[3]));
    int srcA = l15 + 32 * (l4 & 1);
    int srcB = srcA + 16;
    uint32 a00 = __shfl((int)t0w0, srcA), a01 = __shfl((int)t0w1, srcA);
    uint32 b00 = __shfl((int)t0w0, srcB), b01 = __shfl((int)t0w1, srcB);
    uint32 a10 = __shfl((int)t1w0, srcA), a11 = __shfl((int)t1w1, srcA);
    uint32 b10 = __shfl((int)t1w0, srcB), b11 = __shfl((int)t1w1, srcB);
    bool hi = (l4 >= 2);
    uint4 pw;
    pw.x = hi ? a10 : a00;
    pw.y = hi ? a11 : a01;
    pw.z = hi ? b10 : b00;
    pw.w = hi ? b11 : b01;
    bfx8 bgP = __builtin_bit_cast(bfx8, pw);

    bfx8 afv0 = *(const bfx8*)(const void*)(Vb + (size_t)l15 * NQP + k0 + l4 * 8);
    bfx8 afv1 = *(const bfx8*)(const void*)(Vb + (size_t)(16 + l15) * NQP + k0 + l4 * 8);
#pragma unroll
    for (int r = 0; r < 4; r++) { o0[r] *= sc; o1[r] *= sc; }
    o0 = __builtin_amdgcn_mfma_f32_16x16x32_bf16(afv0, bgP, o0, 0, 0, 0);
    o1 = __builtin_amdgcn_mfma_f32_16x16x32_bf16(afv1, bgP, o1, 0, 0, 0);
  }

  if (q < NQ_) {
    float inv = 1.f / ssum;
    float* op = O + ((size_t)(b * NQ_ + q)) * D_ + h * HD_ + kb4;
    f32x4 r0, r1;
#pragma unroll
    for (int r = 0; r < 4; r++) { r0[r] = o0[r] * inv; r1[r] = o1[r] * inv; }
    *(f32x4*)op = r0;
    *(f32x4*)(op + 16) = r1;
  }
}

// ---------- LayerNorm ----------
__global__ __launch_bounds__(256) void rt_ln(
    const float* __restrict__ X, const float* __restrict__ R,
    const float* __restrict__ g, const float* __restrict__ be,
    float* __restrict__ O, int rows)
{
  int row = blockIdx.x * 4 + (threadIdx.x >> 6);
  int lane = threadIdx.x & 63;
  if (row >= rows) return;
  size_t base = (size_t)row * D_ + lane * 4;
  float4 x = *(const float4*)(X + base);
  float4 r = *(const float4*)(R + base);
  float v0 = x.x + r.x, v1 = x.y + r.y, v2 = x.z + r.z, v3 = x.w + r.w;
  float s = v0 + v1 + v2 + v3;
  float sq = v0*v0 + v1*v1 + v2*v2 + v3*v3;
#pragma unroll
  for (int o = 32; o >= 1; o >>= 1) { s += __shfl_xor(s, o); sq += __shfl_xor(sq, o); }
  float mean = s * (1.f / D_);
  float var  = sq * (1.f / D_) - mean * mean;
  float inv  = 1.f / sqrtf(var + 1e-5f);
  int c = lane * 4;
  float4 gv = *(const float4*)(g + c);
  float4 bv = *(const float4*)(be + c);
  float4 o4;
  o4.x = (v0 - mean) * inv * gv.x + bv.x;
  o4.y = (v1 - mean) * inv * gv.y + bv.y;
  o4.z = (v2 - mean) * inv * gv.z + bv.z;
  o4.w = (v3 - mean) * inv * gv.w + bv.w;
  *(float4*)(O + base) = o4;
}

// ---------- attention-weight softmax ----------
__global__ __launch_bounds__(256) void rt_awsm(float* __restrict__ aw, int groups)
{
  int gidx = blockIdx.x * 256 + threadIdx.x;
  if (gidx >= groups) return;
  float* p = aw + (size_t)gidx * 12;
  float e[12]; float m = -1e30f;
#pragma unroll
  for (int i = 0; i < 12; i++) { e[i] = p[i]; m = fmaxf(m, e[i]); }
  float s = 0.f;
#pragma unroll
  for (int i = 0; i < 12; i++) { e[i] = __expf(e[i] - m); s += e[i]; }
  float inv = 1.f / s;
#pragma unroll
  for (int i = 0; i < 12; i++) p[i] = e[i] * inv;
}

// ---------- deformable sampling: thread = (b,q,h, hd-octet) ----------
// 8 channels per thread; each corner load is a 16B uint4 (8 bf16).
__device__ inline void rt_acc8(const ushort16* p, float wgt, float* acc) {
  uint4 v = *(const uint4*)(const void*)p;
  acc[0] += wgt * __uint_as_float(v.x << 16);
  acc[1] += wgt * __uint_as_float(v.x & 0xffff0000u);
  acc[2] += wgt * __uint_as_float(v.y << 16);
  acc[3] += wgt * __uint_as_float(v.y & 0xffff0000u);
  acc[4] += wgt * __uint_as_float(v.z << 16);
  acc[5] += wgt * __uint_as_float(v.z & 0xffff0000u);
  acc[6] += wgt * __uint_as_float(v.w << 16);
  acc[7] += wgt * __uint_as_float(v.w & 0xffff0000u);
}

__global__ __launch_bounds__(256) void rt_deform(
    const ushort16* __restrict__ value,   // [B][H][S][HD] bf16
    const float* __restrict__ off,        // [B][NQ][H][L][P][2]
    const float* __restrict__ aw,         // [B][NQ][H][12]
    const float* __restrict__ ref,        // [B][NQ][1][4]
    float* __restrict__ O)                // [B][NQ][D]
{
  int gid = blockIdx.x * 256 + threadIdx.x;   // M1*H*4 threads
  int hd0 = (gid & 3) * 8;
  int bqh = gid >> 2;
  int h   = bqh & 7;
  int bq  = bqh >> 3;
  int b   = bq / NQ_;
  const float* rp = ref + (size_t)bq * 4;
  float rx = rp[0], ry = rp[1];
  float rw = rp[2] * 0.125f, rh = rp[3] * 0.125f;
  const float* op = off + (size_t)bqh * 24;
  const float* ap = aw  + (size_t)bqh * 12;
  const ushort16* vb = value + ((size_t)b * H_ + h) * (size_t)S_ * HD_ + hd0;
  float acc[8];
#pragma unroll
  for (int i = 0; i < 8; i++) acc[i] = 0.f;
  const int starts[3] = {0, 6400, 8000};
  const int dims[3]   = {80, 40, 20};
#pragma unroll
  for (int l = 0; l < L_; l++) {
    const int Wl = dims[l];
    const ushort16* vl = vb + (size_t)starts[l] * HD_;
#pragma unroll
    for (int p = 0; p < P_; p++) {
      int ip = l * P_ + p;
      float w = ap[ip];
      float x = (rx + op[ip*2+0] * rw) * Wl - 0.5f;
      float y = (ry + op[ip*2+1] * rh) * Wl - 0.5f;
      float x0f = floorf(x), y0f = floorf(y);
      int   x0 = (int)x0f,  y0 = (int)y0f;
      float wx1 = x - x0f, wy1 = y - y0f;
      float wx0 = 1.f - wx1, wy0 = 1.f - wy1;
      bool xok0 = (x0 >= 0) & (x0 < Wl), xok1 = (x0+1 >= 0) & (x0+1 < Wl);
      bool yok0 = (y0 >= 0) & (y0 < Wl), yok1 = (y0+1 >= 0) & (y0+1 < Wl);
      const ushort16* r0p = vl + (size_t)(y0 * Wl) * HD_;
      const ushort16* r1p = r0p + (size_t)Wl * HD_;
      if (xok0 & yok0) rt_acc8(r0p + (size_t)x0 * HD_,     w * wx0 * wy0, acc);
      if (xok1 & yok0) rt_acc8(r0p + (size_t)(x0+1) * HD_, w * wx1 * wy0, acc);
      if (xok0 & yok1) rt_acc8(r1p + (size_t)x0 * HD_,     w * wx0 * wy1, acc);
      if (xok1 & yok1) rt_acc8(r1p + (size_t)(x0+1) * HD_, w * wx1 * wy1, acc);
    }
  }
  float* outp = O + (size_t)bq * D_ + h * HD_ + hd0;
  float4 a0, a1;
  a0.x = acc[0]; a0.y = acc[1]; a0.z = acc[2]; a0.w = acc[3];
  a1.x = acc[4]; a1.y = acc[5]; a1.z = acc[6]; a1.w = acc[7];
  *(float4*)outp = a0;
  *(float4*)(outp + 4) = a1;
}

// ---------- launch ----------
extern "C" void kernel_launch(void* const* d_in, const int* in_sizes, int n_in,
                              void* d_out, int out_size, void* d_ws, size_t ws_size,
                              hipStream_t stream)
{
  const float* hs   = (const float*)d_in[0];
  const float* pos  = (const float*)d_in[1];
  const float* ref  = (const float*)d_in[2];
  const float* ehs  = (const float*)d_in[3];
  const float* Wq   = (const float*)d_in[4];
  const float* Wk   = (const float*)d_in[5];
  const float* Wv   = (const float*)d_in[6];
  const float* Wo   = (const float*)d_in[7];
  const float* Woff = (const float*)d_in[8];
  const float* Waw  = (const float*)d_in[9];
  const float* Wval = (const float*)d_in[10];
  const float* Wout = (const float*)d_in[11];
  const float* W1   = (const float*)d_in[12];
  const float* W2   = (const float*)d_in[13];
  const float* bq   = (const float*)d_in[14];
  const float* bk   = (const float*)d_in[15];
  const float* bvv  = (const float*)d_in[16];
  const float* bo   = (const float*)d_in[17];
  const float* boff = (const float*)d_in[18];
  const float* baw  = (const float*)d_in[19];
  const float* bval = (const float*)d_in[20];
  const float* bout = (const float*)d_in[21];
  const float* b1   = (const float*)d_in[22];
  const float* b2   = (const float*)d_in[23];
  const float* ln1g = (const float*)d_in[24];
  const float* ln1b = (const float*)d_in[25];
  const float* ln2g = (const float*)d_in[26];
  const float* ln2b = (const float*)d_in[27];
  const float* ln3g = (const float*)d_in[28];
  const float* ln3b = (const float*)d_in[29];
  float* out = (float*)d_out;

  float* ws = (float*)d_ws;
  ushort16* value = (ushort16*)ws;
  float* hp   = ws + 34406400;
  float* t0   = ws + 36864000;
  float* t1   = ws + 39321600;
  float* hs1  = ws + 41779200;
  float* hs2  = ws + 44236800;
  float* offb = ws + 46694400;
  float* awb  = ws + 48537600;
  float* ffn1 = ws + 49459200;
  ushort16* qh = (ushort16*)(ws + 59289600);
  ushort16* kh = (ushort16*)(ws + 60600320);
  ushort16* vh = (ushort16*)(ws + 61911040);
  ushort16* vt = (ushort16*)(ws + 63221760);
  ushort16* wbase = (ushort16*)(ws + 64532480);
  ushort16* WqT   = wbase;
  ushort16* WkT   = WqT   + 65536;
  ushort16* WvT   = WkT   + 65536;
  ushort16* WoT   = WvT   + 65536;
  ushort16* WoffT = WoT   + 65536;
  ushort16* WawT  = WoffT + 65536;
  ushort16* WvalT = WawT  + 32768;
  ushort16* WoutT = WvalT + 65536;
  ushort16* W1T   = WoutT + 65536;
  ushort16* W2T   = W1T   + 262144;

  const float qscale = 0.17677669529663687f;

  rt_wt<<<dim3(8, 8),  256, 0, stream>>>(Wq,   WqT,   256, 256, 256);
  rt_wt<<<dim3(8, 8),  256, 0, stream>>>(Wk,   WkT,   256, 256, 256);
  rt_wt<<<dim3(8, 8),  256, 0, stream>>>(Wv,   WvT,   256, 256, 256);
  rt_wt<<<dim3(8, 8),  256, 0, stream>>>(Wo,   WoT,   256, 256, 256);
  rt_wt<<<dim3(8, 8),  256, 0, stream>>>(Woff, WoffT, 256, 192, 256);
  rt_wt<<<dim3(4, 8),  256, 0, stream>>>(Waw,  WawT,  256,  96, 128);
  rt_wt<<<dim3(8, 8),  256, 0, stream>>>(Wval, WvalT, 256, 256, 256);
  rt_wt<<<dim3(8, 8),  256, 0, stream>>>(Wout, WoutT, 256, 256, 256);
  rt_wt<<<dim3(32, 8), 256, 0, stream>>>(W1,   W1T,   256, 1024, 1024);
  rt_wt<<<dim3(8, 32), 256, 0, stream>>>(W2,   W2T,   1024, 256, 256);

  rt_mgemm<<<dim3(2, MV/GBM), 256, 0, stream>>>(ehs, WvalT, bval, nullptr, value,
                                                MV, D_, D_, 1.f, 2);
  rt_add<<<dim3(M1*D_/4/256), 256, 0, stream>>>(hs, pos, hp, M1*D_/4);
  rt_mgemm<<<dim3(2, M1/GBM), 256, 0, stream>>>(hp, WqT, bq,  nullptr, qh, M1, D_, D_, qscale, 3);
  rt_mgemm<<<dim3(2, M1/GBM), 256, 0, stream>>>(hp, WkT, bk,  nullptr, kh, M1, D_, D_, 1.f, 3);
  rt_mgemm<<<dim3(2, M1/GBM), 256, 0, stream>>>(hs, WvT, bvv, nullptr, vh, M1, D_, D_, 1.f, 3);
  rt_vtr<<<dim3(B_*H_), 256, 0, stream>>>(vh, vt);
  rt_fattn<<<dim3(B_*H_*NQT/4), 256, 0, stream>>>(qh, kh, vt, t0);
  rt_mgemm<<<dim3(2, M1/GBM), 256, 0, stream>>>(t0, WoT, bo, t1, nullptr, M1, D_, D_, 1.f, 0);
  rt_ln<<<dim3(M1/4), 256, 0, stream>>>(hs, t1, ln1g, ln1b, hs1, M1);
  rt_add<<<dim3(M1*D_/4/256), 256, 0, stream>>>(hs1, pos, hp, M1*D_/4);
  rt_mgemm<<<dim3(2, M1/GBM), 256, 0, stream>>>(hp, WoffT, boff, offb, nullptr, M1, 192, D_, 1.f, 0);
  rt_mgemm<<<dim3(1, M1/GBM), 256, 0, stream>>>(hp, WawT,  baw,  awb,  nullptr, M1,  96, D_, 1.f, 0);
  rt_awsm<<<dim3(B_*NQ_*H_/256), 256, 0, stream>>>(awb, B_*NQ_*H_);
  rt_deform<<<dim3(M1*H_*4/256), 256, 0, stream>>>(value, offb, awb, ref, t0);
  rt_mgemm<<<dim3(2, M1/GBM), 256, 0, stream>>>(t0, WoutT, bout, t1, nullptr, M1, D_, D_, 1.f, 0);
  rt_ln<<<dim3(M1/4), 256, 0, stream>>>(hs1, t1, ln2g, ln2b, hs2, M1);
  rt_mgemm<<<dim3(8, M1/GBM), 256, 0, stream>>>(hs2, W1T, b1, ffn1, nullptr, M1, FFN_, D_, 1.f, 1);
  rt_mgemm<<<dim3(2, M1/GBM), 256, 0, stream>>>(ffn1, W2T, b2, t1, nullptr, M1, D_, FFN_, 1.f, 0);
  rt_ln<<<dim3(M1/4), 256, 0, stream>>>(hs2, t1, ln3g, ln3b, out, M1);
}

// Round 5
// 484.979 us; speedup vs baseline: 2.8863x; 1.0321x over previous
//
#include <hip/hip_runtime.h>
#include <hip/hip_bf16.h>

typedef unsigned int  uint32;
typedef unsigned short ushort16;
typedef __bf16 bfx8 __attribute__((ext_vector_type(8)));
typedef float  f32x4 __attribute__((ext_vector_type(4)));

typedef __attribute__((address_space(1))) const unsigned int gas_u32;
typedef __attribute__((address_space(3))) unsigned int las_u32;

#define B_   32
#define NQ_  300
#define D_   256
#define H_   8
#define HD_  32
#define L_   3
#define P_   4
#define S_   8400
#define FFN_ 1024
#define M1   (B_*NQ_)    // 9600
#define MV   (B_*S_)     // 268800
#define NQP  320
#define NQT  19

// ---------- helpers ----------
__device__ inline ushort16 f2bf(float x) {
  uint32 u = __float_as_uint(x);
  uint32 r = u + 0x7fffu + ((u >> 16) & 1u);
  return (ushort16)(r >> 16);
}
__device__ inline float bf2f(ushort16 v) {
  return __uint_as_float(((uint32)v) << 16);
}
__device__ inline uint32 cvtpk(float lo, float hi) {
  uint32 r; asm("v_cvt_pk_bf16_f32 %0, %1, %2" : "=v"(r) : "v"(lo), "v"(hi)); return r;
}

// ---------- elementwise add ----------
__global__ __launch_bounds__(256) void rt_add(const float* __restrict__ a,
                                              const float* __restrict__ b,
                                              float* __restrict__ o, int n4)
{
  int i = blockIdx.x * 256 + threadIdx.x;
  if (i < n4) {
    float4 x = ((const float4*)a)[i];
    float4 y = ((const float4*)b)[i];
    float4 z; z.x = x.x + y.x; z.y = x.y + y.y; z.z = x.z + y.z; z.w = x.w + y.w;
    ((float4*)o)[i] = z;
  }
}

// ---------- weight transpose+convert ----------
__global__ __launch_bounds__(256) void rt_wt(const float* __restrict__ W,
                                             ushort16* __restrict__ WT,
                                             int K, int N, int Npad)
{
  __shared__ float t[32][33];
  int n0 = blockIdx.x * 32, k0 = blockIdx.y * 32;
  int c = threadIdx.x & 31, r = threadIdx.x >> 5;
#pragma unroll
  for (int i = 0; i < 4; i++) {
    int kk = k0 + r + i * 8;
    int nn = n0 + c;
    t[r + i * 8][c] = (nn < N) ? W[(size_t)kk * N + nn] : 0.f;
  }
  __syncthreads();
#pragma unroll
  for (int i = 0; i < 4; i++) {
    int nn = n0 + r + i * 8;
    int kk = k0 + c;
    if (nn < Npad) WT[(size_t)nn * K + kk] = f2bf(t[c][r + i * 8]);
  }
}

// ---------- pipelined value GEMM: 128x256 tile, 8 waves, gload_lds for B ----------
// C[row,col] = A[M,K]f32 @ BT[256,K]bf16^T + bias -> bf16 scatter value[b][h][s][hd]
__global__ __launch_bounds__(512, 4) void rt_vgemm(
    const float* __restrict__ A, const ushort16* __restrict__ BT,
    const float* __restrict__ bias, ushort16* __restrict__ Vout,
    int M, int K)
{
  __shared__ __align__(16) char ldsA[2][8192];    // [kc 0..3][m 0..127] 16B chunks
  __shared__ __align__(16) char ldsB[2][16384];   // [kc 0..3][n 0..255] 16B chunks
  const int tid  = threadIdx.x;
  const int lane = tid & 63, w = tid >> 6;
  const int l15  = lane & 15, l4 = lane >> 4;
  const int wr   = (w >> 2) * 64, wc = (w & 3) * 64;
  const int bm   = blockIdx.x * 128;

  const float*    Ap = A  + (size_t)(bm + (tid & 127)) * K + (tid >> 7) * 8;
  const ushort16* Bp = BT + (size_t)(tid & 255) * K + (tid >> 8) * 8;

  f32x4 acc[4][4];
#pragma unroll
  for (int i = 0; i < 4; i++)
#pragma unroll
    for (int j = 0; j < 4; j++)
      acc[i][j] = (f32x4){0.f, 0.f, 0.f, 0.f};

  const int nk = K / 32;

  // prologue: stage t=0 into buf 0
  {
    f32x4 a0 = *(const f32x4*)(Ap);
    f32x4 a1 = *(const f32x4*)(Ap + 4);
    __builtin_amdgcn_global_load_lds((gas_u32*)(const void*)(Bp),
                                     (las_u32*)(void*)(&ldsB[0][tid * 16]), 16, 0, 0);
    __builtin_amdgcn_global_load_lds((gas_u32*)(const void*)(Bp + 16),
                                     (las_u32*)(void*)(&ldsB[0][tid * 16 + 8192]), 16, 0, 0);
    uint4 u;
    u.x = cvtpk(a0[0], a0[1]); u.y = cvtpk(a0[2], a0[3]);
    u.z = cvtpk(a1[0], a1[1]); u.w = cvtpk(a1[2], a1[3]);
    *(uint4*)&ldsA[0][tid * 16] = u;
  }
  __syncthreads();

  int buf = 0;
  for (int t = 0; t < nk; ++t) {
    f32x4 na0, na1;
    if (t + 1 < nk) {
      na0 = *(const f32x4*)(Ap + (t + 1) * 32);
      na1 = *(const f32x4*)(Ap + (t + 1) * 32 + 4);
      __builtin_amdgcn_global_load_lds((gas_u32*)(const void*)(Bp + (t + 1) * 32),
                                       (las_u32*)(void*)(&ldsB[buf ^ 1][tid * 16]), 16, 0, 0);
      __builtin_amdgcn_global_load_lds((gas_u32*)(const void*)(Bp + (t + 1) * 32 + 16),
                                       (las_u32*)(void*)(&ldsB[buf ^ 1][tid * 16 + 8192]), 16, 0, 0);
    }
    bfx8 af[4], bg[4];
#pragma unroll
    for (int mi = 0; mi < 4; mi++)
      af[mi] = *(const bfx8*)&ldsA[buf][l4 * 2048 + (wr + mi * 16 + l15) * 16];
#pragma unroll
    for (int ni = 0; ni < 4; ni++)
      bg[ni] = *(const bfx8*)&ldsB[buf][l4 * 4096 + (wc + ni * 16 + l15) * 16];
#pragma unroll
    for (int mi = 0; mi < 4; mi++)
#pragma unroll
      for (int ni = 0; ni < 4; ni++)
        acc[mi][ni] = __builtin_amdgcn_mfma_f32_16x16x32_bf16(af[mi], bg[ni], acc[mi][ni], 0, 0, 0);
    if (t + 1 < nk) {
      uint4 u;
      u.x = cvtpk(na0[0], na0[1]); u.y = cvtpk(na0[2], na0[3]);
      u.z = cvtpk(na1[0], na1[1]); u.w = cvtpk(na1[2], na1[3]);
      *(uint4*)&ldsA[buf ^ 1][tid * 16] = u;
    }
    __syncthreads();
    buf ^= 1;
  }

#pragma unroll
  for (int mi = 0; mi < 4; mi++) {
#pragma unroll
    for (int ni = 0; ni < 4; ni++) {
      int col = wc + ni * 16 + l15;
      float bv = bias[col];
      int hh = col >> 5, hd = col & 31;
#pragma unroll
      for (int r = 0; r < 4; r++) {
        int row = bm + wr + mi * 16 + l4 * 4 + r;
        int bb = row / S_, s = row - bb * S_;
        Vout[(((size_t)bb * H_ + hh) * S_ + s) * HD_ + hd] = f2bf(acc[mi][ni][r] + bv);
      }
    }
  }
}

// ---------- MFMA bf16 GEMM (generic) ----------
#define GBM 128
#define GBN 128
#define GBK 32
#define LDP 40

__global__ __launch_bounds__(256) void rt_mgemm(
    const float* __restrict__ A, const ushort16* __restrict__ BT,
    const float* __restrict__ bias, float* __restrict__ C,
    ushort16* __restrict__ Sc,
    int M, int N, int K, float scale, int mode)
{
  __shared__ __align__(16) ushort16 As[GBM][LDP];
  __shared__ __align__(16) ushort16 Bs[GBN][LDP];
  const int tid  = threadIdx.x;
  const int lane = tid & 63;
  const int w    = tid >> 6;
  const int wr   = (w >> 1) * 64;
  const int wc   = (w & 1) * 64;
  const int bm   = blockIdx.y * GBM;
  const int bn   = blockIdx.x * GBN;
  const int l15  = lane & 15;
  const int l4   = lane >> 4;

  f32x4 acc[4][4];
#pragma unroll
  for (int i = 0; i < 4; i++)
#pragma unroll
    for (int j = 0; j < 4; j++)
      acc[i][j] = (f32x4){0.f, 0.f, 0.f, 0.f};

  const int arow = tid >> 3, akc = tid & 7;
  const int brow = tid >> 2, bkc = tid & 3;

  for (int k0 = 0; k0 < K; k0 += GBK) {
#pragma unroll
    for (int i = 0; i < 4; i++) {
      int row = arow + i * 32;
      f32x4 v = *(const f32x4*)(A + (size_t)(bm + row) * K + k0 + akc * 4);
      uint2 u;
      u.x = (uint32)f2bf(v.x) | ((uint32)f2bf(v.y) << 16);
      u.y = (uint32)f2bf(v.z) | ((uint32)f2bf(v.w) << 16);
      *(uint2*)(&As[row][akc * 4]) = u;
    }
#pragma unroll
    for (int i = 0; i < 2; i++) {
      int row = brow + i * 64;
      uint4 v = *(const uint4*)(BT + (size_t)(bn + row) * K + k0 + bkc * 8);
      *(uint4*)(&Bs[row][bkc * 8]) = v;
    }
    __syncthreads();

    bfx8 af[4], bg[4];
#pragma unroll
    for (int mi = 0; mi < 4; mi++)
      af[mi] = *(const bfx8*)(&As[wr + mi * 16 + l15][l4 * 8]);
#pragma unroll
    for (int ni = 0; ni < 4; ni++)
      bg[ni] = *(const bfx8*)(&Bs[wc + ni * 16 + l15][l4 * 8]);
#pragma unroll
    for (int mi = 0; mi < 4; mi++)
#pragma unroll
      for (int ni = 0; ni < 4; ni++)
        acc[mi][ni] = __builtin_amdgcn_mfma_f32_16x16x32_bf16(af[mi], bg[ni], acc[mi][ni], 0, 0, 0);
    __syncthreads();
  }

#pragma unroll
  for (int mi = 0; mi < 4; mi++) {
#pragma unroll
    for (int ni = 0; ni < 4; ni++) {
      int col = bn + wc + ni * 16 + l15;
      if (col >= N) continue;
      float bv = bias[col];
#pragma unroll
      for (int r = 0; r < 4; r++) {
        int row = bm + wr + mi * 16 + l4 * 4 + r;
        float vv = (acc[mi][ni][r] + bv) * scale;
        if (mode == 1) vv = fmaxf(vv, 0.f);
        if (mode == 2) {
          int bb = row / S_, s = row - bb * S_;
          int hh = col >> 5, hd = col & 31;
          Sc[(((size_t)bb * H_ + hh) * S_ + s) * HD_ + hd] = f2bf(vv);
        } else if (mode == 3) {
          int bb = row / NQ_, q = row - bb * NQ_;
          int hh = col >> 5, hd = col & 31;
          Sc[(((size_t)bb * H_ + hh) * NQP + q) * HD_ + hd] = f2bf(vv);
        } else {
          C[(size_t)row * N + col] = vv;
        }
      }
    }
  }
}

// ---------- V transpose per (b,h) ----------
__global__ __launch_bounds__(256) void rt_vtr(const ushort16* __restrict__ vh,
                                              ushort16* __restrict__ vt)
{
  __shared__ ushort16 t[64][33];
  int bh = blockIdx.x;
  const ushort16* src = vh + (size_t)bh * NQP * HD_;
  ushort16* dst = vt + (size_t)bh * HD_ * NQP;
  int tid = threadIdx.x;
  int lrow = tid >> 2, lc8 = (tid & 3) * 8;
  int ohd = tid >> 3, oq8 = (tid & 7) * 8;
  for (int r0 = 0; r0 < NQP; r0 += 64) {
    uint4 v = *(const uint4*)(src + (size_t)(r0 + lrow) * HD_ + lc8);
    ushort16* tp = &t[lrow][lc8];
    tp[0] = (ushort16)(v.x & 0xffff); tp[1] = (ushort16)(v.x >> 16);
    tp[2] = (ushort16)(v.y & 0xffff); tp[3] = (ushort16)(v.y >> 16);
    tp[4] = (ushort16)(v.z & 0xffff); tp[5] = (ushort16)(v.z >> 16);
    tp[6] = (ushort16)(v.w & 0xffff); tp[7] = (ushort16)(v.w >> 16);
    __syncthreads();
    uint4 o;
    o.x = (uint32)t[oq8 + 0][ohd] | ((uint32)t[oq8 + 1][ohd] << 16);
    o.y = (uint32)t[oq8 + 2][ohd] | ((uint32)t[oq8 + 3][ohd] << 16);
    o.z = (uint32)t[oq8 + 4][ohd] | ((uint32)t[oq8 + 5][ohd] << 16);
    o.w = (uint32)t[oq8 + 6][ohd] | ((uint32)t[oq8 + 7][ohd] << 16);
    *(uint4*)(dst + (size_t)ohd * NQP + r0 + oq8) = o;
    __syncthreads();
  }
}

// ---------- MFMA flash self-attention ----------
__global__ __launch_bounds__(256) void rt_fattn(
    const ushort16* __restrict__ qh, const ushort16* __restrict__ kh,
    const ushort16* __restrict__ vt, float* __restrict__ O)
{
  int gw  = blockIdx.x * 4 + (threadIdx.x >> 6);
  int bh  = gw / NQT, qt = gw - bh * NQT;
  int b   = bh >> 3, h = bh & 7;
  int lane = threadIdx.x & 63;
  int l15 = lane & 15, l4 = lane >> 4;
  int kb4 = l4 * 4;
  const ushort16* Qb = qh + (size_t)bh * NQP * HD_;
  const ushort16* Kb = kh + (size_t)bh * NQP * HD_;
  const ushort16* Vb = vt + (size_t)bh * HD_ * NQP;
  int q = qt * 16 + l15;

  bfx8 bgQ = *(const bfx8*)(const void*)(Qb + (size_t)q * HD_ + l4 * 8);
  f32x4 o0 = {0.f,0.f,0.f,0.f}, o1 = {0.f,0.f,0.f,0.f};
  float m = -1e30f, ssum = 0.f;

  for (int k0 = 0; k0 < NQP; k0 += 32) {
    bfx8 afk0 = *(const bfx8*)(const void*)(Kb + (size_t)(k0 + l15) * HD_ + l4 * 8);
    bfx8 afk1 = *(const bfx8*)(const void*)(Kb + (size_t)(k0 + 16 + l15) * HD_ + l4 * 8);
    f32x4 z = {0.f,0.f,0.f,0.f};
    f32x4 s0 = __builtin_amdgcn_mfma_f32_16x16x32_bf16(afk0, bgQ, z, 0, 0, 0);
    f32x4 s1 = __builtin_amdgcn_mfma_f32_16x16x32_bf16(afk1, bgQ, z, 0, 0, 0);
    int ka = k0 + kb4, kbb = k0 + 16 + kb4;
#pragma unroll
    for (int r = 0; r < 4; r++) {
      if (ka  + r >= NQ_) s0[r] = -1e30f;
      if (kbb + r >= NQ_) s1[r] = -1e30f;
    }
    float cm = fmaxf(fmaxf(fmaxf(s0[0], s0[1]), fmaxf(s0[2], s0[3])),
                     fmaxf(fmaxf(s1[0], s1[1]), fmaxf(s1[2], s1[3])));
    cm = fmaxf(cm, __shfl_xor(cm, 16));
    cm = fmaxf(cm, __shfl_xor(cm, 32));
    float nm = fmaxf(m, cm);
    float sc = __expf(m - nm);
    m = nm;
    f32x4 p0, p1;
#pragma unroll
    for (int r = 0; r < 4; r++) { p0[r] = __expf(s0[r] - m); p1[r] = __expf(s1[r] - m); }
    float ls = (p0[0]+p0[1]+p0[2]+p0[3]) + (p1[0]+p1[1]+p1[2]+p1[3]);
    ls += __shfl_xor(ls, 16);
    ls += __shfl_xor(ls, 32);
    ssum = ssum * sc + ls;

    uint32 t0w0 = cvtpk(p0[0], p0[1]);
    uint32 t0w1 = cvtpk(p0[2], p0[3]);
    uint32 t1w0 = cvtpk(p1[0], p1[1]);
    uint32 t1w1 = cvtpk(p1[2], p1[3]);
    int srcA = l15 + 32 * (l4 & 1);
    int srcB = srcA + 16;
    uint32 a00 = __shfl((int)t0w0, srcA), a01 = __shfl((int)t0w1, srcA);
    uint32 b00 = __shfl((int)t0w0, srcB), b01 = __shfl((int)t0w1, srcB);
    uint32 a10 = __shfl((int)t1w0, srcA), a11 = __shfl((int)t1w1, srcA);
    uint32 b10 = __shfl((int)t1w0, srcB), b11 = __shfl((int)t1w1, srcB);
    bool hi = (l4 >= 2);
    uint4 pw;
    pw.x = hi ? a10 : a00;
    pw.y = hi ? a11 : a01;
    pw.z = hi ? b10 : b00;
    pw.w = hi ? b11 : b01;
    bfx8 bgP = __builtin_bit_cast(bfx8, pw);

    bfx8 afv0 = *(const bfx8*)(const void*)(Vb + (size_t)l15 * NQP + k0 + l4 * 8);
    bfx8 afv1 = *(const bfx8*)(const void*)(Vb + (size_t)(16 + l15) * NQP + k0 + l4 * 8);
#pragma unroll
    for (int r = 0; r < 4; r++) { o0[r] *= sc; o1[r] *= sc; }
    o0 = __builtin_amdgcn_mfma_f32_16x16x32_bf16(afv0, bgP, o0, 0, 0, 0);
    o1 = __builtin_amdgcn_mfma_f32_16x16x32_bf16(afv1, bgP, o1, 0, 0, 0);
  }

  if (q < NQ_) {
    float inv = 1.f / ssum;
    float* op = O + ((size_t)(b * NQ_ + q)) * D_ + h * HD_ + kb4;
    f32x4 r0, r1;
#pragma unroll
    for (int r = 0; r < 4; r++) { r0[r] = o0[r] * inv; r1[r] = o1[r] * inv; }
    *(f32x4*)op = r0;
    *(f32x4*)(op + 16) = r1;
  }
}

// ---------- LayerNorm ----------
__global__ __launch_bounds__(256) void rt_ln(
    const float* __restrict__ X, const float* __restrict__ R,
    const float* __restrict__ g, const float* __restrict__ be,
    float* __restrict__ O, int rows)
{
  int row = blockIdx.x * 4 + (threadIdx.x >> 6);
  int lane = threadIdx.x & 63;
  if (row >= rows) return;
  size_t base = (size_t)row * D_ + lane * 4;
  float4 x = *(const float4*)(X + base);
  float4 r = *(const float4*)(R + base);
  float v0 = x.x + r.x, v1 = x.y + r.y, v2 = x.z + r.z, v3 = x.w + r.w;
  float s = v0 + v1 + v2 + v3;
  float sq = v0*v0 + v1*v1 + v2*v2 + v3*v3;
#pragma unroll
  for (int o = 32; o >= 1; o >>= 1) { s += __shfl_xor(s, o); sq += __shfl_xor(sq, o); }
  float mean = s * (1.f / D_);
  float var  = sq * (1.f / D_) - mean * mean;
  float inv  = 1.f / sqrtf(var + 1e-5f);
  int c = lane * 4;
  float4 gv = *(const float4*)(g + c);
  float4 bv = *(const float4*)(be + c);
  float4 o4;
  o4.x = (v0 - mean) * inv * gv.x + bv.x;
  o4.y = (v1 - mean) * inv * gv.y + bv.y;
  o4.z = (v2 - mean) * inv * gv.z + bv.z;
  o4.w = (v3 - mean) * inv * gv.w + bv.w;
  *(float4*)(O + base) = o4;
}

// ---------- attention-weight softmax ----------
__global__ __launch_bounds__(256) void rt_awsm(float* __restrict__ aw, int groups)
{
  int gidx = blockIdx.x * 256 + threadIdx.x;
  if (gidx >= groups) return;
  float* p = aw + (size_t)gidx * 12;
  float e[12]; float m = -1e30f;
#pragma unroll
  for (int i = 0; i < 12; i++) { e[i] = p[i]; m = fmaxf(m, e[i]); }
  float s = 0.f;
#pragma unroll
  for (int i = 0; i < 12; i++) { e[i] = __expf(e[i] - m); s += e[i]; }
  float inv = 1.f / s;
#pragma unroll
  for (int i = 0; i < 12; i++) p[i] = e[i] * inv;
}

// ---------- deformable sampling: thread = (b,q,h, hd-octet) ----------
__device__ inline void rt_acc8(const ushort16* p, float wgt, float* acc) {
  uint4 v = *(const uint4*)(const void*)p;
  acc[0] += wgt * __uint_as_float(v.x << 16);
  acc[1] += wgt * __uint_as_float(v.x & 0xffff0000u);
  acc[2] += wgt * __uint_as_float(v.y << 16);
  acc[3] += wgt * __uint_as_float(v.y & 0xffff0000u);
  acc[4] += wgt * __uint_as_float(v.z << 16);
  acc[5] += wgt * __uint_as_float(v.z & 0xffff0000u);
  acc[6] += wgt * __uint_as_float(v.w << 16);
  acc[7] += wgt * __uint_as_float(v.w & 0xffff0000u);
}

__global__ __launch_bounds__(256) void rt_deform(
    const ushort16* __restrict__ value,
    const float* __restrict__ off,
    const float* __restrict__ aw,
    const float* __restrict__ ref,
    float* __restrict__ O)
{
  int gid = blockIdx.x * 256 + threadIdx.x;
  int hd0 = (gid & 3) * 8;
  int bqh = gid >> 2;
  int h   = bqh & 7;
  int bq  = bqh >> 3;
  int b   = bq / NQ_;
  const float* rp = ref + (size_t)bq * 4;
  float rx = rp[0], ry = rp[1];
  float rw = rp[2] * 0.125f, rh = rp[3] * 0.125f;
  const float* op = off + (size_t)bqh * 24;
  const float* ap = aw  + (size_t)bqh * 12;
  const ushort16* vb = value + ((size_t)b * H_ + h) * (size_t)S_ * HD_ + hd0;
  float acc[8];
#pragma unroll
  for (int i = 0; i < 8; i++) acc[i] = 0.f;
  const int starts[3] = {0, 6400, 8000};
  const int dims[3]   = {80, 40, 20};
#pragma unroll
  for (int l = 0; l < L_; l++) {
    const int Wl = dims[l];
    const ushort16* vl = vb + (size_t)starts[l] * HD_;
#pragma unroll
    for (int p = 0; p < P_; p++) {
      int ip = l * P_ + p;
      float w = ap[ip];
      float x = (rx + op[ip*2+0] * rw) * Wl - 0.5f;
      float y = (ry + op[ip*2+1] * rh) * Wl - 0.5f;
      float x0f = floorf(x), y0f = floorf(y);
      int   x0 = (int)x0f,  y0 = (int)y0f;
      float wx1 = x - x0f, wy1 = y - y0f;
      float wx0 = 1.f - wx1, wy0 = 1.f - wy1;
      bool xok0 = (x0 >= 0) & (x0 < Wl), xok1 = (x0+1 >= 0) & (x0+1 < Wl);
      bool yok0 = (y0 >= 0) & (y0 < Wl), yok1 = (y0+1 >= 0) & (y0+1 < Wl);
      const ushort16* r0p = vl + (size_t)(y0 * Wl) * HD_;
      const ushort16* r1p = r0p + (size_t)Wl * HD_;
      if (xok0 & yok0) rt_acc8(r0p + (size_t)x0 * HD_,     w * wx0 * wy0, acc);
      if (xok1 & yok0) rt_acc8(r0p + (size_t)(x0+1) * HD_, w * wx1 * wy0, acc);
      if (xok0 & yok1) rt_acc8(r1p + (size_t)x0 * HD_,     w * wx0 * wy1, acc);
      if (xok1 & yok1) rt_acc8(r1p + (size_t)(x0+1) * HD_, w * wx1 * wy1, acc);
    }
  }
  float* outp = O + (size_t)bq * D_ + h * HD_ + hd0;
  float4 a0, a1;
  a0.x = acc[0]; a0.y = acc[1]; a0.z = acc[2]; a0.w = acc[3];
  a1.x = acc[4]; a1.y = acc[5]; a1.z = acc[6]; a1.w = acc[7];
  *(float4*)outp = a0;
  *(float4*)(outp + 4) = a1;
}

// ---------- launch ----------
extern "C" void kernel_launch(void* const* d_in, const int* in_sizes, int n_in,
                              void* d_out, int out_size, void* d_ws, size_t ws_size,
                              hipStream_t stream)
{
  const float* hs   = (const float*)d_in[0];
  const float* pos  = (const float*)d_in[1];
  const float* ref  = (const float*)d_in[2];
  const float* ehs  = (const float*)d_in[3];
  const float* Wq   = (const float*)d_in[4];
  const float* Wk   = (const float*)d_in[5];
  const float* Wv   = (const float*)d_in[6];
  const float* Wo   = (const float*)d_in[7];
  const float* Woff = (const float*)d_in[8];
  const float* Waw  = (const float*)d_in[9];
  const float* Wval = (const float*)d_in[10];
  const float* Wout = (const float*)d_in[11];
  const float* W1   = (const float*)d_in[12];
  const float* W2   = (const float*)d_in[13];
  const float* bq   = (const float*)d_in[14];
  const float* bk   = (const float*)d_in[15];
  const float* bvv  = (const float*)d_in[16];
  const float* bo   = (const float*)d_in[17];
  const float* boff = (const float*)d_in[18];
  const float* baw  = (const float*)d_in[19];
  const float* bval = (const float*)d_in[20];
  const float* bout = (const float*)d_in[21];
  const float* b1   = (const float*)d_in[22];
  const float* b2   = (const float*)d_in[23];
  const float* ln1g = (const float*)d_in[24];
  const float* ln1b = (const float*)d_in[25];
  const float* ln2g = (const float*)d_in[26];
  const float* ln2b = (const float*)d_in[27];
  const float* ln3g = (const float*)d_in[28];
  const float* ln3b = (const float*)d_in[29];
  float* out = (float*)d_out;

  float* ws = (float*)d_ws;
  ushort16* value = (ushort16*)ws;
  float* hp   = ws + 34406400;
  float* t0   = ws + 36864000;
  float* t1   = ws + 39321600;
  float* hs1  = ws + 41779200;
  float* hs2  = ws + 44236800;
  float* offb = ws + 46694400;
  float* awb  = ws + 48537600;
  float* ffn1 = ws + 49459200;
  ushort16* qh = (ushort16*)(ws + 59289600);
  ushort16* kh = (ushort16*)(ws + 60600320);
  ushort16* vh = (ushort16*)(ws + 61911040);
  ushort16* vt = (ushort16*)(ws + 63221760);
  ushort16* wbase = (ushort16*)(ws + 64532480);
  ushort16* WqT   = wbase;
  ushort16* WkT   = WqT   + 65536;
  ushort16* WvT   = WkT   + 65536;
  ushort16* WoT   = WvT   + 65536;
  ushort16* WoffT = WoT   + 65536;
  ushort16* WawT  = WoffT + 65536;
  ushort16* WvalT = WawT  + 32768;
  ushort16* WoutT = WvalT + 65536;
  ushort16* W1T   = WoutT + 65536;
  ushort16* W2T   = W1T   + 262144;

  const float qscale = 0.17677669529663687f;

  rt_wt<<<dim3(8, 8),  256, 0, stream>>>(Wq,   WqT,   256, 256, 256);
  rt_wt<<<dim3(8, 8),  256, 0, stream>>>(Wk,   WkT,   256, 256, 256);
  rt_wt<<<dim3(8, 8),  256, 0, stream>>>(Wv,   WvT,   256, 256, 256);
  rt_wt<<<dim3(8, 8),  256, 0, stream>>>(Wo,   WoT,   256, 256, 256);
  rt_wt<<<dim3(8, 8),  256, 0, stream>>>(Woff, WoffT, 256, 192, 256);
  rt_wt<<<dim3(4, 8),  256, 0, stream>>>(Waw,  WawT,  256,  96, 128);
  rt_wt<<<dim3(8, 8),  256, 0, stream>>>(Wval, WvalT, 256, 256, 256);
  rt_wt<<<dim3(8, 8),  256, 0, stream>>>(Wout, WoutT, 256, 256, 256);
  rt_wt<<<dim3(32, 8), 256, 0, stream>>>(W1,   W1T,   256, 1024, 1024);
  rt_wt<<<dim3(8, 32), 256, 0, stream>>>(W2,   W2T,   1024, 256, 256);

  // value projection: pipelined 128x256 kernel
  rt_vgemm<<<dim3(MV/128), 512, 0, stream>>>(ehs, WvalT, bval, value, MV, D_);

  rt_add<<<dim3(M1*D_/4/256), 256, 0, stream>>>(hs, pos, hp, M1*D_/4);
  rt_mgemm<<<dim3(2, M1/GBM), 256, 0, stream>>>(hp, WqT, bq,  nullptr, qh, M1, D_, D_, qscale, 3);
  rt_mgemm<<<dim3(2, M1/GBM), 256, 0, stream>>>(hp, WkT, bk,  nullptr, kh, M1, D_, D_, 1.f, 3);
  rt_mgemm<<<dim3(2, M1/GBM), 256, 0, stream>>>(hs, WvT, bvv, nullptr, vh, M1, D_, D_, 1.f, 3);
  rt_vtr<<<dim3(B_*H_), 256, 0, stream>>>(vh, vt);
  rt_fattn<<<dim3(B_*H_*NQT/4), 256, 0, stream>>>(qh, kh, vt, t0);
  rt_mgemm<<<dim3(2, M1/GBM), 256, 0, stream>>>(t0, WoT, bo, t1, nullptr, M1, D_, D_, 1.f, 0);
  rt_ln<<<dim3(M1/4), 256, 0, stream>>>(hs, t1, ln1g, ln1b, hs1, M1);
  rt_add<<<dim3(M1*D_/4/256), 256, 0, stream>>>(hs1, pos, hp, M1*D_/4);
  rt_mgemm<<<dim3(2, M1/GBM), 256, 0, stream>>>(hp, WoffT, boff, offb, nullptr, M1, 192, D_, 1.f, 0);
  rt_mgemm<<<dim3(1, M1/GBM), 256, 0, stream>>>(hp, WawT,  baw,  awb,  nullptr, M1,  96, D_, 1.f, 0);
  rt_awsm<<<dim3(B_*NQ_*H_/256), 256, 0, stream>>>(awb, B_*NQ_*H_);
  rt_deform<<<dim3(M1*H_*4/256), 256, 0, stream>>>(value, offb, awb, ref, t0);
  rt_mgemm<<<dim3(2, M1/GBM), 256, 0, stream>>>(t0, WoutT, bout, t1, nullptr, M1, D_, D_, 1.f, 0);
  rt_ln<<<dim3(M1/4), 256, 0, stream>>>(hs1, t1, ln2g, ln2b, hs2, M1);
  rt_mgemm<<<dim3(8, M1/GBM), 256, 0, stream>>>(hs2, W1T, b1, ffn1, nullptr, M1, FFN_, D_, 1.f, 1);
  rt_mgemm<<<dim3(2, M1/GBM), 256, 0, stream>>>(ffn1, W2T, b2, t1, nullptr, M1, D_, FFN_, 1.f, 0);
  rt_ln<<<dim3(M1/4), 256, 0, stream>>>(hs2, t1, ln3g, ln3b, out, M1);
}